// Round 7
// baseline (878.097 us; speedup 1.0000x reference)
//
#include <hip/hip_runtime.h>
#include <hip/hip_bf16.h>
#include <math.h>

#define TOK   8192
#define DM    512
#define DFFN  2048
#define NE0   4
#define NE1   8

typedef __bf16 bf16;
typedef __bf16 bf16x8 __attribute__((ext_vector_type(8)));
typedef float  f32x4  __attribute__((ext_vector_type(4)));

__device__ __forceinline__ double wave_sum_f64(double v){
#pragma unroll
  for (int o = 32; o > 0; o >>= 1) v += __shfl_down(v, o, 64);
  return v;
}
__device__ __forceinline__ float wave_sum_f32(float v){
#pragma unroll
  for (int o = 32; o > 0; o >>= 1) v += __shfl_down(v, o, 64);
  return v;
}

// async global->LDS, 16B per lane; LDS dest = wave-uniform base + lane*16 (linear in tid).
__device__ __forceinline__ void gload16(const bf16* g, bf16* l){
  __builtin_amdgcn_global_load_lds(
      (const __attribute__((address_space(1))) void*)g,
      (__attribute__((address_space(3))) void*)l, 16, 0, 0);
}

// ---------------- prep kernels ----------------
__global__ void f32_to_bf16(const float* __restrict__ in, bf16* __restrict__ out, int n){
  int i = blockIdx.x*256 + threadIdx.x;
  if (i < n) out[i] = (bf16)in[i];
}

// in [E][K][N] fp32 -> out [E][N][K] bf16 (hi, optional lo)
__global__ void transpose_convert(const float* __restrict__ in, bf16* __restrict__ hi,
                                  bf16* __restrict__ lo, int K, int N){
  __shared__ float tile[64][65];
  int e  = blockIdx.z;
  int n0 = blockIdx.x*64, k0 = blockIdx.y*64;
  const float* src = in + (size_t)e*K*N;
  int c = threadIdx.x & 63, r4 = threadIdx.x >> 6;
#pragma unroll
  for (int i = 0; i < 16; ++i){
    int r = r4*16 + i;
    tile[r][c] = src[(size_t)(k0 + r)*N + n0 + c];
  }
  __syncthreads();
  bf16* dh = hi + (size_t)e*K*N;
  bf16* dl = lo ? (lo + (size_t)e*K*N) : nullptr;
#pragma unroll
  for (int i = 0; i < 16; ++i){
    int r = r4*16 + i;               // n-dim
    float v = tile[c][r];
    size_t o = (size_t)(n0 + r)*K + k0 + c;
    bf16 h = (bf16)v;
    dh[o] = h;
    if (dl) dl[o] = (bf16)(v - (float)h);
  }
}

// c[e][d] = b2[e][d] + sum_f relu(b1[e][f]) * W2[e][f][d]
__global__ void compute_c(const float* __restrict__ W2, const float* __restrict__ b1,
                          const float* __restrict__ b2, float* __restrict__ c){
  int gid = blockIdx.x*256 + threadIdx.x;      // e*DM + d
  int e = gid >> 9, d = gid & (DM-1);
  int fc = blockIdx.y;
  float acc = (fc == 0) ? b2[gid] : 0.f;
  const float* w  = W2 + (size_t)e*DFFN*DM + (size_t)fc*256*DM + d;
  const float* bb = b1 + e*DFFN + fc*256;
#pragma unroll 4
  for (int f = 0; f < 256; ++f) acc += fmaxf(bb[f], 0.f) * w[(size_t)f*DM];
  atomicAdd(&c[gid], acc);
}

// M[row=e*DFFN+f][p] = sum_d W2_0[e][f][d]*Wr1[d][p]   — one wave per row
__global__ void compute_M(const float* __restrict__ W2_0, const float* __restrict__ Wr1,
                          float* __restrict__ M, int nrows){
  int wv = threadIdx.x >> 6, lane = threadIdx.x & 63;
  int row = blockIdx.x*4 + wv;
  if (row >= nrows) return;
  const float* w = W2_0 + (size_t)row*DM + lane*8;
  float w8[8];
#pragma unroll
  for (int q = 0; q < 8; ++q) w8[q] = w[q];
  double acc[8] = {0,0,0,0,0,0,0,0};
#pragma unroll
  for (int q = 0; q < 8; ++q){
    const float* wr = Wr1 + (size_t)(lane*8 + q)*NE1;
#pragma unroll
    for (int p = 0; p < 8; ++p) acc[p] += (double)w8[q]*(double)wr[p];
  }
#pragma unroll
  for (int p = 0; p < 8; ++p) acc[p] = wave_sum_f64(acc[p]);
  if (lane == 0){
#pragma unroll
    for (int p = 0; p < 8; ++p) M[(size_t)row*8 + p] = (float)acc[p];
  }
}

__global__ void compute_cb_proj(const float* __restrict__ c0, const float* __restrict__ b2_0,
                                const float* __restrict__ Wr1, double* __restrict__ c0p,
                                double* __restrict__ b2p){
  int t = threadIdx.x;
  if (t >= NE0*NE1) return;
  int e = t >> 3, p = t & 7;
  double a = 0.0, b = 0.0;
  for (int d = 0; d < DM; ++d){
    double w = (double)Wr1[d*NE1 + p];
    a += (double)c0[e*DM + d]  * w;
    b += (double)b2_0[e*DM + d]* w;
  }
  c0p[t] = a; b2p[t] = b;
}

__global__ void prefix_offs(const int* __restrict__ counts, int NE, int* __restrict__ offs){
  if (threadIdx.x == 0){
    int s = 0;
    for (int e = 0; e < NE; ++e){ offs[e] = s; s += counts[e]; }
    offs[NE] = s;
  }
}

// ---------------- routers (no atomics — probs + top-2 idx; router0 also splits x) ----------------
__global__ void router0_kernel(const float* __restrict__ x, const float* __restrict__ Wr0,
                               float* __restrict__ probs0, int* __restrict__ idx0,
                               bf16* __restrict__ xhi, bf16* __restrict__ xlo){
  int wv = threadIdx.x >> 6, lane = threadIdx.x & 63;
  int t = blockIdx.x*4 + wv;
  const float* xr = x + (size_t)t*DM + lane*8;
  float xv[8];
#pragma unroll
  for (int i = 0; i < 8; ++i) xv[i] = xr[i];
  // fused split-convert: write hi/lo bf16 copies of x
  bf16x8 hv, lv;
#pragma unroll
  for (int i = 0; i < 8; ++i){
    bf16 h = (bf16)xv[i];
    hv[i] = h;
    lv[i] = (bf16)(xv[i] - (float)h);
  }
  *(bf16x8*)(xhi + (size_t)t*DM + lane*8) = hv;
  *(bf16x8*)(xlo + (size_t)t*DM + lane*8) = lv;

  double lg[NE0];
#pragma unroll
  for (int e = 0; e < NE0; ++e){
    double s = 0.0;
#pragma unroll
    for (int i = 0; i < 8; ++i) s += (double)xv[i] * (double)Wr0[(lane*8 + i)*NE0 + e];
    lg[e] = wave_sum_f64(s);
  }
  if (lane == 0){
    double m = lg[0];
#pragma unroll
    for (int e = 1; e < NE0; ++e) m = fmax(m, lg[e]);
    double den = 0.0, ex[NE0];
#pragma unroll
    for (int e = 0; e < NE0; ++e){ ex[e] = exp(lg[e] - m); den += ex[e]; }
    float pf[NE0];
#pragma unroll
    for (int e = 0; e < NE0; ++e){ pf[e] = (float)(ex[e]/den); probs0[t*NE0 + e] = pf[e]; }
    int e0 = 0;
#pragma unroll
    for (int e = 1; e < NE0; ++e) if (pf[e] > pf[e0]) e0 = e;
    int e1 = (e0 == 0) ? 1 : 0;
#pragma unroll
    for (int e = 0; e < NE0; ++e) if (e != e0 && pf[e] > pf[e1]) e1 = e;
    idx0[t*2 + 0] = e0; idx0[t*2 + 1] = e1;
  }
}

__global__ void router1_kernel(const float* __restrict__ proj, const float* __restrict__ probs0,
                               const int* __restrict__ idx0, const double* __restrict__ c0p,
                               const double* __restrict__ b2p, float* __restrict__ probs1,
                               int* __restrict__ idx1){
  int t = blockIdx.x*256 + threadIdx.x;
  float p0[NE0];
#pragma unroll
  for (int e = 0; e < NE0; ++e) p0[e] = probs0[t*NE0 + e];
  double lg[NE1];
#pragma unroll
  for (int p = 0; p < NE1; ++p){
    double s = 0.0;
#pragma unroll
    for (int e = 0; e < NE0; ++e) s += (double)p0[e] * c0p[e*NE1 + p];
    lg[p] = s;
  }
#pragma unroll
  for (int sl = 0; sl < 2; ++sl){
    int e = idx0[t*2 + sl];
    double pe = (double)p0[e];
    const float* pr = proj + ((size_t)(sl*TOK + t))*NE1;
#pragma unroll
    for (int p = 0; p < NE1; ++p) lg[p] += pe * ((double)pr[p] + b2p[e*NE1 + p] - c0p[e*NE1 + p]);
  }
  double m = lg[0];
#pragma unroll
  for (int p = 1; p < NE1; ++p) m = fmax(m, lg[p]);
  double den = 0.0, ex[NE1];
#pragma unroll
  for (int p = 0; p < NE1; ++p){ ex[p] = exp(lg[p] - m); den += ex[p]; }
  float pf[NE1];
#pragma unroll
  for (int p = 0; p < NE1; ++p){ pf[p] = (float)(ex[p]/den); probs1[t*NE1 + p] = pf[p]; }
  int e0 = 0;
#pragma unroll
  for (int p = 1; p < NE1; ++p) if (pf[p] > pf[e0]) e0 = p;
  int e1 = (e0 == 0) ? 1 : 0;
#pragma unroll
  for (int p = 0; p < NE1; ++p) if (p != e0 && pf[p] > pf[e1]) e1 = p;
  idx1[t*2 + 0] = e0; idx1[t*2 + 1] = e1;
}

// Build expert lists from idx with 3-level atomic aggregation.
__global__ void build_lists(const int* __restrict__ idx, int NE,
                            int* __restrict__ list, int* __restrict__ counts){
  __shared__ int lcnt[8];
  __shared__ int lbase[8];
  const int tid = threadIdx.x, lane = tid & 63;
  if (tid < NE) lcnt[tid] = 0;
  __syncthreads();
  const int g = blockIdx.x*1024 + tid;          // 0..2*TOK-1
  const int slot = g >> 13;                     // TOK = 8192
  const int t = g & (TOK-1);
  const int e = idx[t*2 + slot];
  int wbase = 0, rank = 0;
  for (int ee = 0; ee < NE; ++ee){
    unsigned long long m = __ballot(e == ee);
    if (e == ee){
      int leader = __builtin_ctzll(m);
      int b = 0;
      if (lane == leader) b = atomicAdd(&lcnt[ee], (int)__popcll(m));
      wbase = __shfl(b, leader, 64);
      rank  = (int)__popcll(m & ((1ull << lane) - 1ull));
    }
  }
  __syncthreads();
  if (tid < NE) lbase[tid] = atomicAdd(&counts[tid], lcnt[tid]);
  __syncthreads();
  list[e*TOK + lbase[e] + wbase + rank] = slot*TOK + t;
}

// tgt[t][d] = sum_e probs[t][e]*c[e][d]
__global__ void init_combine(const float* __restrict__ probs, const float* __restrict__ c,
                             int NE, float* __restrict__ tgt){
  int gid = blockIdx.x*256 + threadIdx.x;
  int t = gid >> 9, d = gid & (DM-1);
  float v = 0.f;
  for (int e = 0; e < NE; ++e) v += probs[t*NE + e] * c[e*DM + d];
  tgt[gid] = v;
}

// proj[r][p] += sum_{f in chunk} (hi+lo)[rr][f] * Mproj[e][f0+f][p]   — wave per row, no atomics
__global__ void proj_from_h(const bf16* __restrict__ Hb, const bf16* __restrict__ Hlo,
                            int FC, int f0, const float* __restrict__ Mproj,
                            const int* __restrict__ list, const int* __restrict__ offs,
                            float* __restrict__ proj){
  int wv = threadIdx.x >> 6, lane = threadIdx.x & 63;
  int rr = blockIdx.x*4 + wv;
  if (rr >= offs[NE0]) return;
  int e = 0;
#pragma unroll
  for (int k = 1; k < NE0; ++k) if (rr >= offs[k]) e = k;
  int r = list[e*TOK + (rr - offs[e])];
  const bf16* hh = Hb  + (size_t)rr*FC;
  const bf16* hl = Hlo + (size_t)rr*FC;
  const float* Me = Mproj + ((size_t)e*DFFN + f0)*8;
  float acc[8] = {0,0,0,0,0,0,0,0};
  for (int c = 0; c < FC; c += 512){
    int fl = c + lane*8;
    if (fl < FC){
      bf16x8 a = *(const bf16x8*)(hh + fl);
      bf16x8 b = *(const bf16x8*)(hl + fl);
#pragma unroll
      for (int q = 0; q < 8; ++q){
        float hv = (float)a[q] + (float)b[q];
        const f32x4* mp = (const f32x4*)(Me + (size_t)(fl + q)*8);
        f32x4 m0 = mp[0], m1 = mp[1];
#pragma unroll
        for (int p = 0; p < 4; ++p){
          acc[p]   += hv * m0[p];
          acc[4+p] += hv * m1[p];
        }
      }
    }
  }
#pragma unroll
  for (int p = 0; p < 8; ++p) acc[p] = wave_sum_f32(acc[p]);
  if (lane == 0){
#pragma unroll
    for (int p = 0; p < 8; ++p) proj[(size_t)r*8 + p] += acc[p];
  }
}

// ---------------- GEMMs ----------------
// Counted-vmcnt double-buffered pipeline. Per step:
// s_waitcnt vmcnt(8) -> s_barrier -> ds_read+MFMA (all sub-tiles) -> lgkmcnt(0) ->
// s_barrier -> stage(k+2). Loads never drained to 0 inside the loop.
// SPLIT=1: BK=32, 4 tiles/stage (hi*hi + hi*lo + lo*hi fused), 48 MFMA/wave/step.
// SPLIT=0: BK=64, 2 sub-tiles of 32 cols/stage, 32 MFMA/wave/step.
// ffn2:    BK=64, 2 sub-tiles, 32 MFMA/wave/step (was 16 at BK=32).

// FFN1: Hb[compact_row][n-f0] = relu(A[t]@W1[e][:,n] + b1[e][n])
template<int SPLIT>
__global__ __launch_bounds__(256, 2) void gemm_ffn1(
    const bf16* __restrict__ Ahi, const bf16* __restrict__ Alo,
    const bf16* __restrict__ Bhi, const bf16* __restrict__ Blo,   // [E][DFFN][DM]
    const float* __restrict__ b1,
    const int* __restrict__ list, const int* __restrict__ counts,
    const int* __restrict__ offs,
    bf16* __restrict__ Hb, bf16* __restrict__ Hlo, int f0, int FC)
{
  constexpr int BUFE  = 16384;                  // 32 KiB per staging buffer (both paths)
  __shared__ alignas(16) bf16 smem[2*BUFE];     // 64 KiB; Cs epilogue (17408) fits

  const int e   = blockIdx.z;
  const int cnt = counts[e];
  // XCD-aware bijective remap (NCH==1 only): XCD keeps a fixed pair of weight n-tiles in L2.
  const int bx = blockIdx.x, by = blockIdx.y;
  int xl, yl;
  if (gridDim.y == 16){
    xl = ((by >> 1) << 3) + (bx >> 3);
    yl = ((bx & 7) << 1) + (by & 1);
  } else { xl = bx; yl = by; }
  const int m0 = xl * 128;
  if (m0 >= cnt) return;
  const int rbase = offs[e] + m0;
  const int n0  = yl * 128;                   // local within chunk
  const int ng0 = f0 + n0;

  const int tid  = threadIdx.x;
  const int lane = tid & 63, wv = tid >> 6;
  const int wm = wv >> 1, wn = wv & 1;
  const int quad = lane >> 4, l15 = lane & 15;
  const int* le = list + e*TOK;

  // staging geometry: 2 passes of 64 rows; 4 threads/row, 16B chunks swizzled
  const int strow = tid >> 2;                 // 0..63
  const int ch8   = (((tid & 3) ^ ((tid >> 3) & 3)) << 3);
  int growR[2];
#pragma unroll
  for (int p = 0; p < 2; ++p){
    int m = m0 + p*64 + strow;
    growR[p] = (m < cnt) ? (le[m] & (TOK-1)) : 0;
  }
  const bf16* Bh = Bhi + (size_t)e*DFFN*DM;
  const bf16* Bl = SPLIT ? (Blo + (size_t)e*DFFN*DM) : nullptr;

  f32x4 acc[4][4];
#pragma unroll
  for (int i = 0; i < 4; ++i)
#pragma unroll
    for (int j = 0; j < 4; ++j) acc[i][j] = (f32x4){0.f,0.f,0.f,0.f};

  // read offsets (elems within a sub-tile of 4096)
  const int swzl = (l15 >> 1) & 3;
  int aPos[4], bPos[4];
#pragma unroll
  for (int i = 0; i < 4; ++i){
    aPos[i] = (wm*256 + (i*16 + l15)*4 + (quad ^ swzl)) * 8;
    bPos[i] = (wn*256 + (i*16 + l15)*4 + (quad ^ swzl)) * 8;
  }

  if (SPLIT){
    // ---- BK=32, 4-tile fused split schedule ----
    auto stage = [&](int ks, int buf){
      const int colo = (ks << 5) + ch8;
      bf16* dst = smem + buf*BUFE;
#pragma unroll
      for (int p = 0; p < 2; ++p){
        gload16(Ahi + (size_t)growR[p]*DM + colo,                  dst +         (p*256 + tid)*8);
        gload16(Bh  + (size_t)(ng0 + p*64 + strow)*DM + colo,      dst + 4096  + (p*256 + tid)*8);
        gload16(Alo + (size_t)growR[p]*DM + colo,                  dst + 8192  + (p*256 + tid)*8);
        gload16(Bl  + (size_t)(ng0 + p*64 + strow)*DM + colo,      dst + 12288 + (p*256 + tid)*8);
      }
    };
    constexpr int NIT = DM/32;                  // 16
    stage(0, 0);
    stage(1, 1);
    int cur = 0;
    for (int ks = 0; ks < NIT; ++ks){
      if (ks + 1 < NIT) asm volatile("s_waitcnt vmcnt(8)" ::: "memory");
      else              asm volatile("s_waitcnt vmcnt(0)" ::: "memory");
      __builtin_amdgcn_sched_barrier(0);
      __builtin_amdgcn_s_barrier();
      __builtin_amdgcn_sched_barrier(0);
      const bf16* B0 = smem + cur*BUFE;
      bf16x8 ah[4], bh[4];
#pragma unroll
      for (int i = 0; i < 4; ++i){
        ah[i] = *(const bf16x8*)&B0[aPos[i]];
        bh[i] = *(const bf16x8*)&B0[4096 + bPos[i]];
      }
#pragma unroll
      for (int i = 0; i < 4; ++i)
#pragma unroll
        for (int j = 0; j < 4; ++j)
          acc[i][j] = __builtin_amdgcn_mfma_f32_16x16x32_bf16(ah[i], bh[j], acc[i][j], 0,0,0);
      bf16x8 t2[4];
#pragma unroll
      for (int i = 0; i < 4; ++i) t2[i] = *(const bf16x8*)&B0[12288 + bPos[i]];   // Blo
#pragma unroll
      for (int i = 0; i < 4; ++i)
#pragma unroll
        for (int j = 0; j < 4; ++j)
          acc[i][j] = __builtin_amdgcn_mfma_f32_16x16x32_bf16(ah[i], t2[j], acc[i][j], 0,0,0);
#pragma unroll
      for (int i = 0; i < 4; ++i) t2[i] = *(const bf16x8*)&B0[8192 + aPos[i]];    // Alo
#pragma unroll
      for (int i = 0; i < 4; ++i)
#pragma unroll
        for (int j = 0; j < 4; ++j)
          acc[i][j] = __builtin_amdgcn_mfma_f32_16x16x32_bf16(t2[i], bh[j], acc[i][j], 0,0,0);
      asm volatile("s_waitcnt lgkmcnt(0)" ::: "memory");
      __builtin_amdgcn_sched_barrier(0);
      __builtin_amdgcn_s_barrier();
      __builtin_amdgcn_sched_barrier(0);
      if (ks + 2 < NIT) stage(ks + 2, cur);
      cur ^= 1;
    }
  } else {
    // ---- BK=64, 2 sub-tiles of 32 cols per stage ----
    auto stage = [&](int ks, int buf){
      bf16* dst = smem + buf*BUFE;
#pragma unroll
      for (int s = 0; s < 2; ++s){
        const int colo = (ks << 6) + (s << 5) + ch8;
        bf16* d2 = dst + s*8192;
#pragma unroll
        for (int p = 0; p < 2; ++p){
          gload16(Ahi + (size_t)growR[p]*DM + colo,             d2 +        (p*256 + tid)*8);
          gload16(Bh  + (size_t)(ng0 + p*64 + strow)*DM + colo, d2 + 4096 + (p*256 + tid)*8);
        }
      }
    };
    constexpr int NIT = DM/64;                  // 8
    stage(0, 0);
    stage(1, 1);
    int cur = 0;
    for (int ks = 0; ks < NIT; ++ks){
      if (ks + 1 < NIT) asm volatile("s_waitcnt vmcnt(8)" ::: "memory");
      else              asm volatile("s_waitcnt vmcnt(0)" ::: "memory");
      __builtin_amdgcn_sched_barrier(0);
      __builtin_amdgcn_s_barrier();
      __builtin_amdgcn_sched_barrier(0);
#pragma unroll
      for (int s = 0; s < 2; ++s){
        const bf16* B0 = smem + cur*BUFE + s*8192;
        bf16x8 a[4], b[4];
#pragma unroll
        for (int i = 0; i < 4; ++i){
          a[i] = *(const bf16x8*)&B0[aPos[i]];
          b[i] = *(const bf16x8*)&B0[4096 + bPos[i]];
        }
#pragma unroll
        for (int i = 0; i < 4; ++i)
#pragma unroll
          for (int j = 0; j < 4; ++j)
            acc[i][j] = __builtin_amdgcn_mfma_f32_16x16x32_bf16(a[i], b[j], acc[i][j], 0,0,0);
      }
      asm volatile("s_waitcnt lgkmcnt(0)" ::: "memory");
      __builtin_amdgcn_sched_barrier(0);
      __builtin_amdgcn_s_barrier();
      __builtin_amdgcn_sched_barrier(0);
      if (ks + 2 < NIT) stage(ks + 2, cur);
      cur ^= 1;
    }
  }

  // ---- epilogue: bias+relu, Cs transpose, vectorized stores ----
  float bjv[4];
#pragma unroll
  for (int j = 0; j < 4; ++j)
    bjv[j] = b1[e*DFFN + ng0 + wn*64 + j*16 + l15];

  bf16* Cs = smem;                                // 128 x 136 (padded)
#pragma unroll
  for (int i = 0; i < 4; ++i)
#pragma unroll
    for (int j = 0; j < 4; ++j)
#pragma unroll
      for (int reg = 0; reg < 4; ++reg){
        float h = fmaxf(acc[i][j][reg] + bjv[j], 0.f);
        Cs[(wm*64 + i*16 + quad*4 + reg)*136 + wn*64 + j*16 + l15] = (bf16)h;
      }
  __syncthreads();
  {
    const int srow = tid >> 1, shalf = (tid & 1) * 64;
    if (m0 + srow < cnt){
      bf16* dst = Hb + (size_t)(rbase + srow)*FC + n0 + shalf;
      const bf16* srcl = &Cs[srow*136 + shalf];
#pragma unroll
      for (int q = 0; q < 8; ++q)
        *(bf16x8*)(dst + q*8) = *(const bf16x8*)(srcl + q*8);
    }
  }
  if (SPLIT){
    __syncthreads();
#pragma unroll
    for (int i = 0; i < 4; ++i)
#pragma unroll
      for (int j = 0; j < 4; ++j)
#pragma unroll
        for (int reg = 0; reg < 4; ++reg){
          float h = fmaxf(acc[i][j][reg] + bjv[j], 0.f);
          bf16 hi = (bf16)h;
          Cs[(wm*64 + i*16 + quad*4 + reg)*136 + wn*64 + j*16 + l15] = (bf16)(h - (float)hi);
        }
    __syncthreads();
    const int srow = tid >> 1, shalf = (tid & 1) * 64;
    if (m0 + srow < cnt){
      bf16* dst = Hlo + (size_t)(rbase + srow)*FC + n0 + shalf;
      const bf16* srcl = &Cs[srow*136 + shalf];
#pragma unroll
      for (int q = 0; q < 8; ++q)
        *(bf16x8*)(dst + q*8) = *(const bf16x8*)(srcl + q*8);
    }
  }
}

// FFN2: tgt[t][n] += probs[t][e]*( Hb[row]@W2[e][f0:f0+FC,n] (+ b2-ce on chunk 0) )
__global__ __launch_bounds__(256, 2) void gemm_ffn2(
    const bf16* __restrict__ Hb, int FC, int f0,
    const bf16* __restrict__ Bt,                // [E][DM][DFFN]
    const float* __restrict__ b2, const float* __restrict__ ce,
    const float* __restrict__ probs, int NE,
    const int* __restrict__ list, const int* __restrict__ counts,
    const int* __restrict__ offs,
    float* __restrict__ tgt, int addBias)
{
  constexpr int BUFE = 16384;                 // BK=64: A 8192 + B 8192 elems per buffer
  __shared__ alignas(16) bf16 smem[2*BUFE];   // 64 KiB

  const int e   = blockIdx.z;
  const int cnt = counts[e];
  // XCD remap: grid (64,4,E); XCD c=bx%8 handles n-tile yl=c>>1 only.
  const int bx = blockIdx.x, by = blockIdx.y;
  const int xl = (bx >> 3) + (((bx & 1) + (by << 1)) << 3);
  const int yl = (bx & 7) >> 1;
  const int m0 = xl*128;
  if (m0 >= cnt) return;
  const int rbase = offs[e];
  const int n0  = yl*128;

  const int tid = threadIdx.x, lane = tid & 63, wv = tid >> 6;
  const int wm = wv >> 1, wn = wv & 1, quad = lane >> 4, l15 = lane & 15;
  const int* le = list + e*TOK;

  const int strow = tid >> 2;
  const int ch8   = (((tid & 3) ^ ((tid >> 3) & 3)) << 3);
  int growR[2];
#pragma unroll
  for (int p = 0; p < 2; ++p){
    int m = m0 + p*64 + strow;
    growR[p] = rbase + ((m < cnt) ? m : (cnt - 1));
  }
  const bf16* Be = Bt + (size_t)e*DM*DFFN;

  f32x4 acc[4][4];
#pragma unroll
  for (int i = 0; i < 4; ++i)
#pragma unroll
    for (int j = 0; j < 4; ++j) acc[i][j] = (f32x4){0.f,0.f,0.f,0.f};

  const int swzl = (l15 >> 1) & 3;
  int aPos[4], bPos[4];
#pragma unroll
  for (int i = 0; i < 4; ++i){
    aPos[i] = (wm*256 + (i*16 + l15)*4 + (quad ^ swzl)) * 8;
    bPos[i] = (wn*256 + (i*16 + l15)*4 + (quad ^ swzl)) * 8;
  }

  auto stage = [&](int ks, int buf){
    bf16* dst = smem + buf*BUFE;
#pragma unroll
    for (int s = 0; s < 2; ++s){
      const int colo = (ks << 6) + (s << 5) + ch8;
      bf16* d2 = dst + s*8192;
#pragma unroll
      for (int p = 0; p < 2; ++p){
        gload16(Hb + (size_t)growR[p]*FC + colo,                       d2 +        (p*256 + tid)*8);
        gload16(Be + (size_t)(n0 + p*64 + strow)*DFFN + f0 + colo,     d2 + 4096 + (p*256 + tid)*8);
      }
    }
  };

  const int NIT = FC/64;
  stage(0, 0);
  stage(1, 1);
  int cur = 0;
  for (int ks = 0; ks < NIT; ++ks){
    if (ks + 1 < NIT) asm volatile("s_waitcnt vmcnt(8)" ::: "memory");
    else              asm volatile("s_waitcnt vmcnt(0)" ::: "memory");
    __builtin_amdgcn_sched_barrier(0);
    __builtin_amdgcn_s_barrier();
    __builtin_amdgcn_sched_barrier(0);
#pragma unroll
    for (int s = 0; s < 2; ++s){
      const bf16* B0 = smem + cur*BUFE + s*8192;
      bf16x8 a[4], b[4];
#pragma unroll
      for (int i = 0; i < 4; ++i){
        a[i] = *(const bf16x8*)&B0[aPos[i]];
        b[i] = *(const bf16x8*)&B0[4096 + bPos[i]];
      }
#pragma unroll
      for (int i = 0; i < 4; ++i)
#pragma unroll
        for (int j = 0; j < 4; ++j)
          acc[i][j] = __builtin_amdgcn_mfma_f32_16x16x32_bf16(a[i], b[j], acc[i][j], 0,0,0);
    }
    asm volatile("s_waitcnt lgkmcnt(0)" ::: "memory");
    __builtin_amdgcn_sched_barrier(0);
    __builtin_amdgcn_s_barrier();
    __builtin_amdgcn_sched_barrier(0);
    if (ks + 2 < NIT) stage(ks + 2, cur);
    cur ^= 1;
  }
#pragma unroll
  for (int i = 0; i < 4; ++i){
#pragma unroll
    for (int reg = 0; reg < 4; ++reg){
      int m = m0 + wm*64 + i*16 + quad*4 + reg;
      if (m >= cnt) continue;
      int r = le[m];
      int t = r & (TOK-1);
      float g = probs[t*NE + e];
#pragma unroll
      for (int j = 0; j < 4; ++j){
        int n = n0 + wn*64 + j*16 + l15;
        float v = acc[i][j][reg];
        if (addBias) v += b2[e*DM + n] - ce[e*DM + n];
        atomicAdd(&tgt[(size_t)t*DM + n], g*v);
      }
    }
  }
}

// ---------------- launch ----------------
extern "C" void kernel_launch(void* const* d_in, const int* in_sizes, int n_in,
                              void* d_out, int out_size, void* d_ws, size_t ws_size,
                              hipStream_t stream)
{
  (void)in_sizes; (void)n_in; (void)out_size;
  const float* x    = (const float*)d_in[0];
  const float* Wr0  = (const float*)d_in[1];
  const float* W1_0 = (const float*)d_in[2];
  const float* b1_0 = (const float*)d_in[3];
  const float* W2_0 = (const float*)d_in[4];
  const float* b2_0 = (const float*)d_in[5];
  const float* Wr1  = (const float*)d_in[6];
  const float* W1_1 = (const float*)d_in[7];
  const float* b1_1 = (const float*)d_in[8];
  const float* W2_1 = (const float*)d_in[9];
  const float* b2_1 = (const float*)d_in[10];
  float* out = (float*)d_out;

  const size_t MB = (size_t)1 << 20;
  char* base = (char*)d_ws;

  bf16* xhi  = (bf16*)base;                 // 8 MB; phase B: h0b
  bf16* h0b  = (bf16*)base;
  bf16* xlo  = (bf16*)(base + 8*MB);        // 8 MB
  bf16* w10h = (bf16*)(base + 16*MB);       // 16 MB; phase B: w11h
  bf16* w10l = (bf16*)(base + 32*MB);       // 16 MB; phase B: w21h
  bf16* w11h = (bf16*)(base + 16*MB);
  bf16* w21h = (bf16*)(base + 32*MB);
  bf16* w20h = (bf16*)(base + 48*MB);       // 16 MB
  float* h0f = (float*)(base + 64*MB);      // 16 MB

  char* mp = base + 80*MB;                  // misc ~2.5 MB
  auto take = [&](size_t n) -> char* { char* p = mp; mp += (n + 255) & ~(size_t)255; return p; };
  float* probs0 = (float*)take((size_t)TOK*NE0*4);
  float* probs1 = (float*)take((size_t)TOK*NE1*4);
  int*   idx0   = (int*)  take((size_t)TOK*2*4);
  int*   idx1   = (int*)  take((size_t)TOK*2*4);
  int*   list0  = (int*)  take((size_t)NE0*TOK*4);
  int*   list1  = (int*)  take((size_t)NE1*TOK*4);
  int*   counts = (int*)  take(256);
  int*   offs0  = (int*)  take(256);
  int*   offs1  = (int*)  take(256);
  float* c0     = (float*)take((size_t)NE0*DM*4);
  float* c1     = (float*)take((size_t)NE1*DM*4);
  float* Mproj  = (float*)take((size_t)NE0*DFFN*NE1*4);
  double* c0p   = (double*)take(NE0*NE1*8);
  double* b2p   = (double*)take(NE0*NE1*8);
  float* proj   = (float*)take((size_t)2*TOK*NE1*4);

  const size_t fixed = 84*MB;
  int NCH;
  if      (ws_size >= fixed + 128*MB) NCH = 1;
  else if (ws_size >= fixed +  64*MB) NCH = 2;
  else if (ws_size >= fixed +  32*MB) NCH = 4;
  else if (ws_size >= fixed +  16*MB) NCH = 8;
  else return;  // workspace too small: clean validation failure, no fault
  const int FC = DFFN / NCH;
  const size_t chunkB = (size_t)2*TOK*FC*2;       // bytes per bf16 chunk buffer
  bf16* Hb   = (bf16*)(base + fixed);
  bf16* Hlo  = (bf16*)(base + fixed + chunkB);

  hipMemsetAsync(counts, 0, 16*sizeof(int), stream);
  hipMemsetAsync(c0, 0, (size_t)(NE0+NE1)*DM*4, stream);   // c0,c1 contiguous
  hipMemsetAsync(proj, 0, (size_t)2*TOK*NE1*4, stream);

  // prep
  transpose_convert<<<dim3(DFFN/64, DM/64, NE0), 256, 0, stream>>>(W1_0, w10h, w10l, DM, DFFN);
  transpose_convert<<<dim3(DM/64, DFFN/64, NE0), 256, 0, stream>>>(W2_0, w20h, nullptr, DFFN, DM);
  compute_c<<<dim3(NE0*DM/256, 8), 256, 0, stream>>>(W2_0, b1_0, b2_0, c0);
  compute_c<<<dim3(NE1*DM/256, 8), 256, 0, stream>>>(W2_1, b1_1, b2_1, c1);
  compute_M<<<dim3(NE0*DFFN/4), 256, 0, stream>>>(W2_0, Wr1, Mproj, NE0*DFFN);
  compute_cb_proj<<<1, 64, 0, stream>>>(c0, b2_0, Wr1, c0p, b2p);

  // level 0
  router0_kernel<<<dim3(TOK/4), 256, 0, stream>>>(x, Wr0, probs0, idx0, xhi, xlo);
  build_lists<<<dim3(2*TOK/1024), 1024, 0, stream>>>(idx0, NE0, list0, counts);
  prefix_offs<<<1, 64, 0, stream>>>(counts, NE0, offs0);
  init_combine<<<dim3(TOK*DM/256), 256, 0, stream>>>(probs0, c0, NE0, h0f);
  for (int c = 0; c < NCH; ++c){
    gemm_ffn1<1><<<dim3(64, FC/128, NE0), 256, 0, stream>>>(
        xhi, xlo, w10h, w10l, b1_0, list0, counts, offs0, Hb, Hlo, c*FC, FC);
    proj_from_h<<<dim3(2*TOK/4), 256, 0, stream>>>(Hb, Hlo, FC, c*FC, Mproj,
                                                   list0, offs0, proj);
    gemm_ffn2<<<dim3(64, DM/128, NE0), 256, 0, stream>>>(
        Hb, FC, c*FC, w20h, b2_0, c0, probs0, NE0, list0, counts, offs0, h0f, (c == 0));
  }

  // transition
  transpose_convert<<<dim3(DFFN/64, DM/64, NE1), 256, 0, stream>>>(W1_1, w11h, nullptr, DM, DFFN);
  transpose_convert<<<dim3(DM/64, DFFN/64, NE1), 256, 0, stream>>>(W2_1, w21h, nullptr, DFFN, DM);
  f32_to_bf16<<<dim3(TOK*DM/256), 256, 0, stream>>>(h0f, h0b, TOK*DM);
  router1_kernel<<<dim3(TOK/256), 256, 0, stream>>>(proj, probs0, idx0, c0p, b2p,
                                                    probs1, idx1);
  build_lists<<<dim3(2*TOK/1024), 1024, 0, stream>>>(idx1, NE1, list1, counts + NE0);
  prefix_offs<<<1, 64, 0, stream>>>(counts + NE0, NE1, offs1);
  init_combine<<<dim3(TOK*DM/256), 256, 0, stream>>>(probs1, c1, NE1, out);

  // level 1
  for (int c = 0; c < NCH; ++c){
    gemm_ffn1<0><<<dim3(64, FC/128, NE1), 256, 0, stream>>>(
        h0b, nullptr, w11h, nullptr, b1_1, list1, counts + NE0, offs1,
        Hb, nullptr, c*FC, FC);
    gemm_ffn2<<<dim3(64, DM/128, NE1), 256, 0, stream>>>(
        Hb, FC, c*FC, w21h, b2_1, c1, probs1, NE1, list1, counts + NE0, offs1, out, (c == 0));
  }
}

// Round 8
// 863.541 us; speedup vs baseline: 1.0169x; 1.0169x over previous
//
#include <hip/hip_runtime.h>
#include <hip/hip_bf16.h>
#include <math.h>

#define TOK   8192
#define DM    512
#define DFFN  2048
#define NE0   4
#define NE1   8

typedef __bf16 bf16;
typedef __bf16 bf16x8 __attribute__((ext_vector_type(8)));
typedef float  f32x4  __attribute__((ext_vector_type(4)));

__device__ __forceinline__ double wave_sum_f64(double v){
#pragma unroll
  for (int o = 32; o > 0; o >>= 1) v += __shfl_down(v, o, 64);
  return v;
}
__device__ __forceinline__ float wave_sum_f32(float v){
#pragma unroll
  for (int o = 32; o > 0; o >>= 1) v += __shfl_down(v, o, 64);
  return v;
}

// async global->LDS, 16B per lane; LDS dest = wave-uniform base + lane*16 (linear in tid).
__device__ __forceinline__ void gload16(const bf16* g, bf16* l){
  __builtin_amdgcn_global_load_lds(
      (const __attribute__((address_space(1))) void*)g,
      (__attribute__((address_space(3))) void*)l, 16, 0, 0);
}

// ---------------- prep kernels ----------------
__global__ void f32_to_bf16(const float* __restrict__ in, bf16* __restrict__ out, int n){
  int i = blockIdx.x*256 + threadIdx.x;
  if (i < n) out[i] = (bf16)in[i];
}

// in [E][K][N] fp32 -> out [E][N][K] bf16 (hi, optional lo)
__global__ void transpose_convert(const float* __restrict__ in, bf16* __restrict__ hi,
                                  bf16* __restrict__ lo, int K, int N){
  __shared__ float tile[64][65];
  int e  = blockIdx.z;
  int n0 = blockIdx.x*64, k0 = blockIdx.y*64;
  const float* src = in + (size_t)e*K*N;
  int c = threadIdx.x & 63, r4 = threadIdx.x >> 6;
#pragma unroll
  for (int i = 0; i < 16; ++i){
    int r = r4*16 + i;
    tile[r][c] = src[(size_t)(k0 + r)*N + n0 + c];
  }
  __syncthreads();
  bf16* dh = hi + (size_t)e*K*N;
  bf16* dl = lo ? (lo + (size_t)e*K*N) : nullptr;
#pragma unroll
  for (int i = 0; i < 16; ++i){
    int r = r4*16 + i;               // n-dim
    float v = tile[c][r];
    size_t o = (size_t)(n0 + r)*K + k0 + c;
    bf16 h = (bf16)v;
    dh[o] = h;
    if (dl) dl[o] = (bf16)(v - (float)h);
  }
}

// c[e][d] = b2[e][d] + sum_f relu(b1[e][f]) * W2[e][f][d]
__global__ void compute_c(const float* __restrict__ W2, const float* __restrict__ b1,
                          const float* __restrict__ b2, float* __restrict__ c){
  int gid = blockIdx.x*256 + threadIdx.x;      // e*DM + d
  int e = gid >> 9, d = gid & (DM-1);
  int fc = blockIdx.y;
  float acc = (fc == 0) ? b2[gid] : 0.f;
  const float* w  = W2 + (size_t)e*DFFN*DM + (size_t)fc*256*DM + d;
  const float* bb = b1 + e*DFFN + fc*256;
#pragma unroll 4
  for (int f = 0; f < 256; ++f) acc += fmaxf(bb[f], 0.f) * w[(size_t)f*DM];
  atomicAdd(&c[gid], acc);
}

// M[row=e*DFFN+f][p] = sum_d W2_0[e][f][d]*Wr1[d][p]   — one wave per row
__global__ void compute_M(const float* __restrict__ W2_0, const float* __restrict__ Wr1,
                          float* __restrict__ M, int nrows){
  int wv = threadIdx.x >> 6, lane = threadIdx.x & 63;
  int row = blockIdx.x*4 + wv;
  if (row >= nrows) return;
  const float* w = W2_0 + (size_t)row*DM + lane*8;
  float w8[8];
#pragma unroll
  for (int q = 0; q < 8; ++q) w8[q] = w[q];
  double acc[8] = {0,0,0,0,0,0,0,0};
#pragma unroll
  for (int q = 0; q < 8; ++q){
    const float* wr = Wr1 + (size_t)(lane*8 + q)*NE1;
#pragma unroll
    for (int p = 0; p < 8; ++p) acc[p] += (double)w8[q]*(double)wr[p];
  }
#pragma unroll
  for (int p = 0; p < 8; ++p) acc[p] = wave_sum_f64(acc[p]);
  if (lane == 0){
#pragma unroll
    for (int p = 0; p < 8; ++p) M[(size_t)row*8 + p] = (float)acc[p];
  }
}

__global__ void compute_cb_proj(const float* __restrict__ c0, const float* __restrict__ b2_0,
                                const float* __restrict__ Wr1, double* __restrict__ c0p,
                                double* __restrict__ b2p){
  int t = threadIdx.x;
  if (t >= NE0*NE1) return;
  int e = t >> 3, p = t & 7;
  double a = 0.0, b = 0.0;
  for (int d = 0; d < DM; ++d){
    double w = (double)Wr1[d*NE1 + p];
    a += (double)c0[e*DM + d]  * w;
    b += (double)b2_0[e*DM + d]* w;
  }
  c0p[t] = a; b2p[t] = b;
}

__global__ void prefix_offs(const int* __restrict__ counts, int NE, int* __restrict__ offs){
  if (threadIdx.x == 0){
    int s = 0;
    for (int e = 0; e < NE; ++e){ offs[e] = s; s += counts[e]; }
    offs[NE] = s;
  }
}

// ---------------- routers (no atomics — probs + top-2 idx; router0 also splits x) ----------------
__global__ void router0_kernel(const float* __restrict__ x, const float* __restrict__ Wr0,
                               float* __restrict__ probs0, int* __restrict__ idx0,
                               bf16* __restrict__ xhi, bf16* __restrict__ xlo){
  int wv = threadIdx.x >> 6, lane = threadIdx.x & 63;
  int t = blockIdx.x*4 + wv;
  const float* xr = x + (size_t)t*DM + lane*8;
  float xv[8];
#pragma unroll
  for (int i = 0; i < 8; ++i) xv[i] = xr[i];
  // fused split-convert: write hi/lo bf16 copies of x
  bf16x8 hv, lv;
#pragma unroll
  for (int i = 0; i < 8; ++i){
    bf16 h = (bf16)xv[i];
    hv[i] = h;
    lv[i] = (bf16)(xv[i] - (float)h);
  }
  *(bf16x8*)(xhi + (size_t)t*DM + lane*8) = hv;
  *(bf16x8*)(xlo + (size_t)t*DM + lane*8) = lv;

  double lg[NE0];
#pragma unroll
  for (int e = 0; e < NE0; ++e){
    double s = 0.0;
#pragma unroll
    for (int i = 0; i < 8; ++i) s += (double)xv[i] * (double)Wr0[(lane*8 + i)*NE0 + e];
    lg[e] = wave_sum_f64(s);
  }
  if (lane == 0){
    double m = lg[0];
#pragma unroll
    for (int e = 1; e < NE0; ++e) m = fmax(m, lg[e]);
    double den = 0.0, ex[NE0];
#pragma unroll
    for (int e = 0; e < NE0; ++e){ ex[e] = exp(lg[e] - m); den += ex[e]; }
    float pf[NE0];
#pragma unroll
    for (int e = 0; e < NE0; ++e){ pf[e] = (float)(ex[e]/den); probs0[t*NE0 + e] = pf[e]; }
    int e0 = 0;
#pragma unroll
    for (int e = 1; e < NE0; ++e) if (pf[e] > pf[e0]) e0 = e;
    int e1 = (e0 == 0) ? 1 : 0;
#pragma unroll
    for (int e = 0; e < NE0; ++e) if (e != e0 && pf[e] > pf[e1]) e1 = e;
    idx0[t*2 + 0] = e0; idx0[t*2 + 1] = e1;
  }
}

__global__ void router1_kernel(const float* __restrict__ proj, const float* __restrict__ probs0,
                               const int* __restrict__ idx0, const double* __restrict__ c0p,
                               const double* __restrict__ b2p, float* __restrict__ probs1,
                               int* __restrict__ idx1){
  int t = blockIdx.x*256 + threadIdx.x;
  float p0[NE0];
#pragma unroll
  for (int e = 0; e < NE0; ++e) p0[e] = probs0[t*NE0 + e];
  double lg[NE1];
#pragma unroll
  for (int p = 0; p < NE1; ++p){
    double s = 0.0;
#pragma unroll
    for (int e = 0; e < NE0; ++e) s += (double)p0[e] * c0p[e*NE1 + p];
    lg[p] = s;
  }
#pragma unroll
  for (int sl = 0; sl < 2; ++sl){
    int e = idx0[t*2 + sl];
    double pe = (double)p0[e];
    const float* pr = proj + ((size_t)(sl*TOK + t))*NE1;
#pragma unroll
    for (int p = 0; p < NE1; ++p) lg[p] += pe * ((double)pr[p] + b2p[e*NE1 + p] - c0p[e*NE1 + p]);
  }
  double m = lg[0];
#pragma unroll
  for (int p = 1; p < NE1; ++p) m = fmax(m, lg[p]);
  double den = 0.0, ex[NE1];
#pragma unroll
  for (int p = 0; p < NE1; ++p){ ex[p] = exp(lg[p] - m); den += ex[p]; }
  float pf[NE1];
#pragma unroll
  for (int p = 0; p < NE1; ++p){ pf[p] = (float)(ex[p]/den); probs1[t*NE1 + p] = pf[p]; }
  int e0 = 0;
#pragma unroll
  for (int p = 1; p < NE1; ++p) if (pf[p] > pf[e0]) e0 = p;
  int e1 = (e0 == 0) ? 1 : 0;
#pragma unroll
  for (int p = 0; p < NE1; ++p) if (p != e0 && pf[p] > pf[e1]) e1 = p;
  idx1[t*2 + 0] = e0; idx1[t*2 + 1] = e1;
}

// Build expert lists from idx with 3-level atomic aggregation.
__global__ void build_lists(const int* __restrict__ idx, int NE,
                            int* __restrict__ list, int* __restrict__ counts){
  __shared__ int lcnt[8];
  __shared__ int lbase[8];
  const int tid = threadIdx.x, lane = tid & 63;
  if (tid < NE) lcnt[tid] = 0;
  __syncthreads();
  const int g = blockIdx.x*1024 + tid;          // 0..2*TOK-1
  const int slot = g >> 13;                     // TOK = 8192
  const int t = g & (TOK-1);
  const int e = idx[t*2 + slot];
  int wbase = 0, rank = 0;
  for (int ee = 0; ee < NE; ++ee){
    unsigned long long m = __ballot(e == ee);
    if (e == ee){
      int leader = __builtin_ctzll(m);
      int b = 0;
      if (lane == leader) b = atomicAdd(&lcnt[ee], (int)__popcll(m));
      wbase = __shfl(b, leader, 64);
      rank  = (int)__popcll(m & ((1ull << lane) - 1ull));
    }
  }
  __syncthreads();
  if (tid < NE) lbase[tid] = atomicAdd(&counts[tid], lcnt[tid]);
  __syncthreads();
  list[e*TOK + lbase[e] + wbase + rank] = slot*TOK + t;
}

// tgt[t][d] = sum_e probs[t][e]*c[e][d]
__global__ void init_combine(const float* __restrict__ probs, const float* __restrict__ c,
                             int NE, float* __restrict__ tgt){
  int gid = blockIdx.x*256 + threadIdx.x;
  int t = gid >> 9, d = gid & (DM-1);
  float v = 0.f;
  for (int e = 0; e < NE; ++e) v += probs[t*NE + e] * c[e*DM + d];
  tgt[gid] = v;
}

// proj[r][p] += sum_{f in chunk} (hi+lo)[rr][f] * Mproj[e][f0+f][p]   — wave per row, no atomics
__global__ void proj_from_h(const bf16* __restrict__ Hb, const bf16* __restrict__ Hlo,
                            int FC, int f0, const float* __restrict__ Mproj,
                            const int* __restrict__ list, const int* __restrict__ offs,
                            float* __restrict__ proj){
  int wv = threadIdx.x >> 6, lane = threadIdx.x & 63;
  int rr = blockIdx.x*4 + wv;
  if (rr >= offs[NE0]) return;
  int e = 0;
#pragma unroll
  for (int k = 1; k < NE0; ++k) if (rr >= offs[k]) e = k;
  int r = list[e*TOK + (rr - offs[e])];
  const bf16* hh = Hb  + (size_t)rr*FC;
  const bf16* hl = Hlo + (size_t)rr*FC;
  const float* Me = Mproj + ((size_t)e*DFFN + f0)*8;
  float acc[8] = {0,0,0,0,0,0,0,0};
  for (int c = 0; c < FC; c += 512){
    int fl = c + lane*8;
    if (fl < FC){
      bf16x8 a = *(const bf16x8*)(hh + fl);
      bf16x8 b = *(const bf16x8*)(hl + fl);
#pragma unroll
      for (int q = 0; q < 8; ++q){
        float hv = (float)a[q] + (float)b[q];
        const f32x4* mp = (const f32x4*)(Me + (size_t)(fl + q)*8);
        f32x4 m0 = mp[0], m1 = mp[1];
#pragma unroll
        for (int p = 0; p < 4; ++p){
          acc[p]   += hv * m0[p];
          acc[4+p] += hv * m1[p];
        }
      }
    }
  }
#pragma unroll
  for (int p = 0; p < 8; ++p) acc[p] = wave_sum_f32(acc[p]);
  if (lane == 0){
#pragma unroll
    for (int p = 0; p < 8; ++p) proj[(size_t)r*8 + p] += acc[p];
  }
}

// ---------------- GEMMs ----------------
// Counted-vmcnt double-buffered pipeline, BK=32 per step (R6-proven config).
// Per step: s_waitcnt vmcnt(N_newer) -> s_barrier -> setprio(1) ds_read+MFMA setprio(0)
// -> lgkmcnt(0) -> s_barrier -> stage(k+2). Loads never drained to 0 inside loop.
// T5 setprio: counted-vmcnt phase structure gives waves role diversity across the
// 2-3 resident blocks; prioritizing the MFMA cluster keeps the matrix pipe fed.

// FFN1: Hb[compact_row][n-f0] = relu(A[t]@W1[e][:,n] + b1[e][n])
// SPLIT=1: fused hi*hi + hi*lo + lo*hi per step (4 tiles staged/step), 48 MFMA/wave/step.
template<int SPLIT>
__global__ __launch_bounds__(256, 2) void gemm_ffn1(
    const bf16* __restrict__ Ahi, const bf16* __restrict__ Alo,
    const bf16* __restrict__ Bhi, const bf16* __restrict__ Blo,   // [E][DFFN][DM]
    const float* __restrict__ b1,
    const int* __restrict__ list, const int* __restrict__ counts,
    const int* __restrict__ offs,
    bf16* __restrict__ Hb, bf16* __restrict__ Hlo, int f0, int FC)
{
  constexpr int BUFE  = SPLIT ? 16384 : 8192;           // elems per staging buffer
  constexpr int SMEME = (2*BUFE > 17408) ? 2*BUFE : 17408;
  __shared__ alignas(16) bf16 smem[SMEME];

  const int e   = blockIdx.z;
  const int cnt = counts[e];
  // XCD-aware bijective remap (NCH==1 only): XCD keeps a fixed pair of weight n-tiles in L2.
  const int bx = blockIdx.x, by = blockIdx.y;
  int xl, yl;
  if (gridDim.y == 16){
    xl = ((by >> 1) << 3) + (bx >> 3);
    yl = ((bx & 7) << 1) + (by & 1);
  } else { xl = bx; yl = by; }
  const int m0 = xl * 128;
  if (m0 >= cnt) return;
  const int rbase = offs[e] + m0;
  const int n0  = yl * 128;                   // local within chunk
  const int ng0 = f0 + n0;

  const int tid  = threadIdx.x;
  const int lane = tid & 63, wv = tid >> 6;
  const int wm = wv >> 1, wn = wv & 1;
  const int quad = lane >> 4, l15 = lane & 15;
  const int* le = list + e*TOK;

  // staging geometry: 2 passes of 64 rows; 4 threads/row, 16B chunks swizzled
  const int strow = tid >> 2;                 // 0..63
  const int ch8   = (((tid & 3) ^ ((tid >> 3) & 3)) << 3);
  int growR[2];
#pragma unroll
  for (int p = 0; p < 2; ++p){
    int m = m0 + p*64 + strow;
    growR[p] = (m < cnt) ? (le[m] & (TOK-1)) : 0;
  }
  const bf16* Bh = Bhi + (size_t)e*DFFN*DM;
  const bf16* Bl = SPLIT ? (Blo + (size_t)e*DFFN*DM) : nullptr;

  f32x4 acc[4][4];
#pragma unroll
  for (int i = 0; i < 4; ++i)
#pragma unroll
    for (int j = 0; j < 4; ++j) acc[i][j] = (f32x4){0.f,0.f,0.f,0.f};

  // read offsets (elems within a tile of 4096)
  const int swzl = (l15 >> 1) & 3;
  int aPos[4], bPos[4];
#pragma unroll
  for (int i = 0; i < 4; ++i){
    aPos[i] = (wm*256 + (i*16 + l15)*4 + (quad ^ swzl)) * 8;
    bPos[i] = (wn*256 + (i*16 + l15)*4 + (quad ^ swzl)) * 8;
  }

  auto stage = [&](int ks, int buf){
    const int colo = (ks << 5) + ch8;
    bf16* dst = smem + buf*BUFE;
#pragma unroll
    for (int p = 0; p < 2; ++p){
      gload16(Ahi + (size_t)growR[p]*DM + colo,                  dst +         (p*256 + tid)*8);
      gload16(Bh  + (size_t)(ng0 + p*64 + strow)*DM + colo,      dst + 4096  + (p*256 + tid)*8);
      if (SPLIT){
        gload16(Alo + (size_t)growR[p]*DM + colo,                dst + 8192  + (p*256 + tid)*8);
        gload16(Bl  + (size_t)(ng0 + p*64 + strow)*DM + colo,    dst + 12288 + (p*256 + tid)*8);
      }
    }
  };

  constexpr int NIT = DM/32;                  // 16
  stage(0, 0);
  stage(1, 1);
  int cur = 0;
  for (int ks = 0; ks < NIT; ++ks){
    if (ks + 1 < NIT){
      if (SPLIT) asm volatile("s_waitcnt vmcnt(8)" ::: "memory");
      else       asm volatile("s_waitcnt vmcnt(4)" ::: "memory");
    } else {
      asm volatile("s_waitcnt vmcnt(0)" ::: "memory");
    }
    __builtin_amdgcn_sched_barrier(0);
    __builtin_amdgcn_s_barrier();
    __builtin_amdgcn_sched_barrier(0);
    __builtin_amdgcn_s_setprio(1);
    const bf16* B0 = smem + cur*BUFE;
    bf16x8 ah[4], bh[4];
#pragma unroll
    for (int i = 0; i < 4; ++i){
      ah[i] = *(const bf16x8*)&B0[aPos[i]];
      bh[i] = *(const bf16x8*)&B0[4096 + bPos[i]];
    }
#pragma unroll
    for (int i = 0; i < 4; ++i)
#pragma unroll
      for (int j = 0; j < 4; ++j)
        acc[i][j] = __builtin_amdgcn_mfma_f32_16x16x32_bf16(ah[i], bh[j], acc[i][j], 0,0,0);
    if (SPLIT){
      bf16x8 t2[4];
#pragma unroll
      for (int i = 0; i < 4; ++i) t2[i] = *(const bf16x8*)&B0[12288 + bPos[i]];   // Blo
#pragma unroll
      for (int i = 0; i < 4; ++i)
#pragma unroll
        for (int j = 0; j < 4; ++j)
          acc[i][j] = __builtin_amdgcn_mfma_f32_16x16x32_bf16(ah[i], t2[j], acc[i][j], 0,0,0);
#pragma unroll
      for (int i = 0; i < 4; ++i) t2[i] = *(const bf16x8*)&B0[8192 + aPos[i]];    // Alo
#pragma unroll
      for (int i = 0; i < 4; ++i)
#pragma unroll
        for (int j = 0; j < 4; ++j)
          acc[i][j] = __builtin_amdgcn_mfma_f32_16x16x32_bf16(t2[i], bh[j], acc[i][j], 0,0,0);
    }
    __builtin_amdgcn_s_setprio(0);
    asm volatile("s_waitcnt lgkmcnt(0)" ::: "memory");
    __builtin_amdgcn_sched_barrier(0);
    __builtin_amdgcn_s_barrier();
    __builtin_amdgcn_sched_barrier(0);
    if (ks + 2 < NIT) stage(ks + 2, cur);
    cur ^= 1;
  }

  // ---- epilogue: bias+relu, Cs transpose, vectorized stores ----
  float bjv[4];
#pragma unroll
  for (int j = 0; j < 4; ++j)
    bjv[j] = b1[e*DFFN + ng0 + wn*64 + j*16 + l15];

  bf16* Cs = smem;                                // 128 x 136 (padded)
#pragma unroll
  for (int i = 0; i < 4; ++i)
#pragma unroll
    for (int j = 0; j < 4; ++j)
#pragma unroll
      for (int reg = 0; reg < 4; ++reg){
        float h = fmaxf(acc[i][j][reg] + bjv[j], 0.f);
        Cs[(wm*64 + i*16 + quad*4 + reg)*136 + wn*64 + j*16 + l15] = (bf16)h;
      }
  __syncthreads();
  {
    const int srow = tid >> 1, shalf = (tid & 1) * 64;
    if (m0 + srow < cnt){
      bf16* dst = Hb + (size_t)(rbase + srow)*FC + n0 + shalf;
      const bf16* srcl = &Cs[srow*136 + shalf];
#pragma unroll
      for (int q = 0; q < 8; ++q)
        *(bf16x8*)(dst + q*8) = *(const bf16x8*)(srcl + q*8);
    }
  }
  if (SPLIT){
    __syncthreads();
#pragma unroll
    for (int i = 0; i < 4; ++i)
#pragma unroll
      for (int j = 0; j < 4; ++j)
#pragma unroll
        for (int reg = 0; reg < 4; ++reg){
          float h = fmaxf(acc[i][j][reg] + bjv[j], 0.f);
          bf16 hi = (bf16)h;
          Cs[(wm*64 + i*16 + quad*4 + reg)*136 + wn*64 + j*16 + l15] = (bf16)(h - (float)hi);
        }
    __syncthreads();
    const int srow = tid >> 1, shalf = (tid & 1) * 64;
    if (m0 + srow < cnt){
      bf16* dst = Hlo + (size_t)(rbase + srow)*FC + n0 + shalf;
      const bf16* srcl = &Cs[srow*136 + shalf];
#pragma unroll
      for (int q = 0; q < 8; ++q)
        *(bf16x8*)(dst + q*8) = *(const bf16x8*)(srcl + q*8);
    }
  }
}

// FFN2: tgt[t][n] += probs[t][e]*( Hb[row]@W2[e][f0:f0+FC,n] (+ b2-ce on chunk 0) )
__global__ __launch_bounds__(256, 3) void gemm_ffn2(
    const bf16* __restrict__ Hb, int FC, int f0,
    const bf16* __restrict__ Bt,                // [E][DM][DFFN]
    const float* __restrict__ b2, const float* __restrict__ ce,
    const float* __restrict__ probs, int NE,
    const int* __restrict__ list, const int* __restrict__ counts,
    const int* __restrict__ offs,
    float* __restrict__ tgt, int addBias)
{
  __shared__ alignas(16) bf16 smem[16384];    // 2 buffers x 8192 elems (32 KiB)

  const int e   = blockIdx.z;
  const int cnt = counts[e];
  // XCD remap: grid (64,4,E); XCD c=bx%8 handles n-tile yl=c>>1 only.
  const int bx = blockIdx.x, by = blockIdx.y;
  const int xl = (bx >> 3) + (((bx & 1) + (by << 1)) << 3);
  const int yl = (bx & 7) >> 1;
  const int m0 = xl*128;
  if (m0 >= cnt) return;
  const int rbase = offs[e];
  const int n0  = yl*128;

  const int tid = threadIdx.x, lane = tid & 63, wv = tid >> 6;
  const int wm = wv >> 1, wn = wv & 1, quad = lane >> 4, l15 = lane & 15;
  const int* le = list + e*TOK;

  const int strow = tid >> 2;
  const int ch8   = (((tid & 3) ^ ((tid >> 3) & 3)) << 3);
  int growR[2];
#pragma unroll
  for (int p = 0; p < 2; ++p){
    int m = m0 + p*64 + strow;
    growR[p] = rbase + ((m < cnt) ? m : (cnt - 1));
  }
  const bf16* Be = Bt + (size_t)e*DM*DFFN;

  f32x4 acc[4][4];
#pragma unroll
  for (int i = 0; i < 4; ++i)
#pragma unroll
    for (int j = 0; j < 4; ++j) acc[i][j] = (f32x4){0.f,0.f,0.f,0.f};

  const int swzl = (l15 >> 1) & 3;
  int aPos[4], bPos[4];
#pragma unroll
  for (int i = 0; i < 4; ++i){
    aPos[i] = (wm*256 + (i*16 + l15)*4 + (quad ^ swzl)) * 8;
    bPos[i] = (wn*256 + (i*16 + l15)*4 + (quad ^ swzl)) * 8;
  }

  auto stage = [&](int ks, int buf){
    const int colo = (ks << 5) + ch8;
    bf16* dst = smem + buf*8192;
#pragma unroll
    for (int p = 0; p < 2; ++p){
      gload16(Hb + (size_t)growR[p]*FC + colo,                       dst +        (p*256 + tid)*8);
      gload16(Be + (size_t)(n0 + p*64 + strow)*DFFN + f0 + colo,     dst + 4096 + (p*256 + tid)*8);
    }
  };

  const int NIT = FC/32;
  stage(0, 0);
  stage(1, 1);
  int cur = 0;
  for (int ks = 0; ks < NIT; ++ks){
    if (ks + 1 < NIT) asm volatile("s_waitcnt vmcnt(4)" ::: "memory");
    else              asm volatile("s_waitcnt vmcnt(0)" ::: "memory");
    __builtin_amdgcn_sched_barrier(0);
    __builtin_amdgcn_s_barrier();
    __builtin_amdgcn_sched_barrier(0);
    __builtin_amdgcn_s_setprio(1);
    const bf16* B0 = smem + cur*8192;
    bf16x8 a[4], b[4];
#pragma unroll
    for (int i = 0; i < 4; ++i){
      a[i] = *(const bf16x8*)&B0[aPos[i]];
      b[i] = *(const bf16x8*)&B0[4096 + bPos[i]];
    }
#pragma unroll
    for (int i = 0; i < 4; ++i)
#pragma unroll
      for (int j = 0; j < 4; ++j)
        acc[i][j] = __builtin_amdgcn_mfma_f32_16x16x32_bf16(a[i], b[j], acc[i][j], 0,0,0);
    __builtin_amdgcn_s_setprio(0);
    asm volatile("s_waitcnt lgkmcnt(0)" ::: "memory");
    __builtin_amdgcn_sched_barrier(0);
    __builtin_amdgcn_s_barrier();
    __builtin_amdgcn_sched_barrier(0);
    if (ks + 2 < NIT) stage(ks + 2, cur);
    cur ^= 1;
  }
#pragma unroll
  for (int i = 0; i < 4; ++i){
#pragma unroll
    for (int reg = 0; reg < 4; ++reg){
      int m = m0 + wm*64 + i*16 + quad*4 + reg;
      if (m >= cnt) continue;
      int r = le[m];
      int t = r & (TOK-1);
      float g = probs[t*NE + e];
#pragma unroll
      for (int j = 0; j < 4; ++j){
        int n = n0 + wn*64 + j*16 + l15;
        float v = acc[i][j][reg];
        if (addBias) v += b2[e*DM + n] - ce[e*DM + n];
        atomicAdd(&tgt[(size_t)t*DM + n], g*v);
      }
    }
  }
}

// ---------------- launch ----------------
extern "C" void kernel_launch(void* const* d_in, const int* in_sizes, int n_in,
                              void* d_out, int out_size, void* d_ws, size_t ws_size,
                              hipStream_t stream)
{
  (void)in_sizes; (void)n_in; (void)out_size;
  const float* x    = (const float*)d_in[0];
  const float* Wr0  = (const float*)d_in[1];
  const float* W1_0 = (const float*)d_in[2];
  const float* b1_0 = (const float*)d_in[3];
  const float* W2_0 = (const float*)d_in[4];
  const float* b2_0 = (const float*)d_in[5];
  const float* Wr1  = (const float*)d_in[6];
  const float* W1_1 = (const float*)d_in[7];
  const float* b1_1 = (const float*)d_in[8];
  const float* W2_1 = (const float*)d_in[9];
  const float* b2_1 = (const float*)d_in[10];
  float* out = (float*)d_out;

  const size_t MB = (size_t)1 << 20;
  char* base = (char*)d_ws;

  bf16* xhi  = (bf16*)base;                 // 8 MB; phase B: h0b
  bf16* h0b  = (bf16*)base;
  bf16* xlo  = (bf16*)(base + 8*MB);        // 8 MB
  bf16* w10h = (bf16*)(base + 16*MB);       // 16 MB; phase B: w11h
  bf16* w10l = (bf16*)(base + 32*MB);       // 16 MB; phase B: w21h
  bf16* w11h = (bf16*)(base + 16*MB);
  bf16* w21h = (bf16*)(base + 32*MB);
  bf16* w20h = (bf16*)(base + 48*MB);       // 16 MB
  float* h0f = (float*)(base + 64*MB);      // 16 MB

  char* mp = base + 80*MB;                  // misc ~2.5 MB
  auto take = [&](size_t n) -> char* { char* p = mp; mp += (n + 255) & ~(size_t)255; return p; };
  float* probs0 = (float*)take((size_t)TOK*NE0*4);
  float* probs1 = (float*)take((size_t)TOK*NE1*4);
  int*   idx0   = (int*)  take((size_t)TOK*2*4);
  int*   idx1   = (int*)  take((size_t)TOK*2*4);
  int*   list0  = (int*)  take((size_t)NE0*TOK*4);
  int*   list1  = (int*)  take((size_t)NE1*TOK*4);
  int*   counts = (int*)  take(256);
  int*   offs0  = (int*)  take(256);
  int*   offs1  = (int*)  take(256);
  float* c0     = (float*)take((size_t)NE0*DM*4);
  float* c1     = (float*)take((size_t)NE1*DM*4);
  float* Mproj  = (float*)take((size_t)NE0*DFFN*NE1*4);
  double* c0p   = (double*)take(NE0*NE1*8);
  double* b2p   = (double*)take(NE0*NE1*8);
  float* proj   = (float*)take((size_t)2*TOK*NE1*4);

  const size_t fixed = 84*MB;
  int NCH;
  if      (ws_size >= fixed + 128*MB) NCH = 1;
  else if (ws_size >= fixed +  64*MB) NCH = 2;
  else if (ws_size >= fixed +  32*MB) NCH = 4;
  else if (ws_size >= fixed +  16*MB) NCH = 8;
  else return;  // workspace too small: clean validation failure, no fault
  const int FC = DFFN / NCH;
  const size_t chunkB = (size_t)2*TOK*FC*2;       // bytes per bf16 chunk buffer
  bf16* Hb   = (bf16*)(base + fixed);
  bf16* Hlo  = (bf16*)(base + fixed + chunkB);

  hipMemsetAsync(counts, 0, 16*sizeof(int), stream);
  hipMemsetAsync(c0, 0, (size_t)(NE0+NE1)*DM*4, stream);   // c0,c1 contiguous
  hipMemsetAsync(proj, 0, (size_t)2*TOK*NE1*4, stream);

  // prep
  transpose_convert<<<dim3(DFFN/64, DM/64, NE0), 256, 0, stream>>>(W1_0, w10h, w10l, DM, DFFN);
  transpose_convert<<<dim3(DM/64, DFFN/64, NE0), 256, 0, stream>>>(W2_0, w20h, nullptr, DFFN, DM);
  compute_c<<<dim3(NE0*DM/256, 8), 256, 0, stream>>>(W2_0, b1_0, b2_0, c0);
  compute_c<<<dim3(NE1*DM/256, 8), 256, 0, stream>>>(W2_1, b1_1, b2_1, c1);
  compute_M<<<dim3(NE0*DFFN/4), 256, 0, stream>>>(W2_0, Wr1, Mproj, NE0*DFFN);
  compute_cb_proj<<<1, 64, 0, stream>>>(c0, b2_0, Wr1, c0p, b2p);

  // level 0
  router0_kernel<<<dim3(TOK/4), 256, 0, stream>>>(x, Wr0, probs0, idx0, xhi, xlo);
  build_lists<<<dim3(2*TOK/1024), 1024, 0, stream>>>(idx0, NE0, list0, counts);
  prefix_offs<<<1, 64, 0, stream>>>(counts, NE0, offs0);
  init_combine<<<dim3(TOK*DM/256), 256, 0, stream>>>(probs0, c0, NE0, h0f);
  for (int c = 0; c < NCH; ++c){
    gemm_ffn1<1><<<dim3(64, FC/128, NE0), 256, 0, stream>>>(
        xhi, xlo, w10h, w10l, b1_0, list0, counts, offs0, Hb, Hlo, c*FC, FC);
    proj_from_h<<<dim3(2*TOK/4), 256, 0, stream>>>(Hb, Hlo, FC, c*FC, Mproj,
                                                   list0, offs0, proj);
    gemm_ffn2<<<dim3(64, DM/128, NE0), 256, 0, stream>>>(
        Hb, FC, c*FC, w20h, b2_0, c0, probs0, NE0, list0, counts, offs0, h0f, (c == 0));
  }

  // transition
  transpose_convert<<<dim3(DFFN/64, DM/64, NE1), 256, 0, stream>>>(W1_1, w11h, nullptr, DM, DFFN);
  transpose_convert<<<dim3(DM/64, DFFN/64, NE1), 256, 0, stream>>>(W2_1, w21h, nullptr, DFFN, DM);
  f32_to_bf16<<<dim3(TOK*DM/256), 256, 0, stream>>>(h0f, h0b, TOK*DM);
  router1_kernel<<<dim3(TOK/256), 256, 0, stream>>>(proj, probs0, idx0, c0p, b2p,
                                                    probs1, idx1);
  build_lists<<<dim3(2*TOK/1024), 1024, 0, stream>>>(idx1, NE1, list1, counts + NE0);
  prefix_offs<<<1, 64, 0, stream>>>(counts + NE0, NE1, offs1);
  init_combine<<<dim3(TOK*DM/256), 256, 0, stream>>>(probs1, c1, NE1, out);

  // level 1
  for (int c = 0; c < NCH; ++c){
    gemm_ffn1<0><<<dim3(64, FC/128, NE1), 256, 0, stream>>>(
        h0b, nullptr, w11h, nullptr, b1_1, list1, counts + NE0, offs1,
        Hb, nullptr, c*FC, FC);
    gemm_ffn2<<<dim3(64, DM/128, NE1), 256, 0, stream>>>(
        Hb, FC, c*FC, w21h, b2_1, c1, probs1, NE1, list1, counts + NE0, offs1, out, (c == 0));
  }
}

// Round 9
// 807.894 us; speedup vs baseline: 1.0869x; 1.0689x over previous
//
#include <hip/hip_runtime.h>
#include <hip/hip_bf16.h>
#include <math.h>

#define TOK   8192
#define DM    512
#define DFFN  2048
#define NE0   4
#define NE1   8

typedef __bf16 bf16;
typedef __bf16 bf16x4 __attribute__((ext_vector_type(4)));
typedef __bf16 bf16x8 __attribute__((ext_vector_type(8)));
typedef float  f32x4  __attribute__((ext_vector_type(4)));

__device__ __forceinline__ double wave_sum_f64(double v){
#pragma unroll
  for (int o = 32; o > 0; o >>= 1) v += __shfl_down(v, o, 64);
  return v;
}
__device__ __forceinline__ float wave_sum_f32(float v){
#pragma unroll
  for (int o = 32; o > 0; o >>= 1) v += __shfl_down(v, o, 64);
  return v;
}

// async global->LDS, 16B per lane; LDS dest = wave-uniform base + lane*16 (linear in tid).
__device__ __forceinline__ void gload16(const bf16* g, bf16* l){
  __builtin_amdgcn_global_load_lds(
      (const __attribute__((address_space(1))) void*)g,
      (__attribute__((address_space(3))) void*)l, 16, 0, 0);
}

// ---------------- prep kernels ----------------
__global__ void f32_to_bf16(const float* __restrict__ in, bf16* __restrict__ out, int n){
  int i = blockIdx.x*256 + threadIdx.x;
  if (i < n) out[i] = (bf16)in[i];
}

// in [E][K][N] fp32 -> out [E][N][K] bf16 (hi, optional lo)
__global__ void transpose_convert(const float* __restrict__ in, bf16* __restrict__ hi,
                                  bf16* __restrict__ lo, int K, int N){
  __shared__ float tile[64][65];
  int e  = blockIdx.z;
  int n0 = blockIdx.x*64, k0 = blockIdx.y*64;
  const float* src = in + (size_t)e*K*N;
  int c = threadIdx.x & 63, r4 = threadIdx.x >> 6;
#pragma unroll
  for (int i = 0; i < 16; ++i){
    int r = r4*16 + i;
    tile[r][c] = src[(size_t)(k0 + r)*N + n0 + c];
  }
  __syncthreads();
  bf16* dh = hi + (size_t)e*K*N;
  bf16* dl = lo ? (lo + (size_t)e*K*N) : nullptr;
#pragma unroll
  for (int i = 0; i < 16; ++i){
    int r = r4*16 + i;               // n-dim
    float v = tile[c][r];
    size_t o = (size_t)(n0 + r)*K + k0 + c;
    bf16 h = (bf16)v;
    dh[o] = h;
    if (dl) dl[o] = (bf16)(v - (float)h);
  }
}

// c[e][d] = b2[e][d] + sum_f relu(b1[e][f]) * W2[e][f][d]
__global__ void compute_c(const float* __restrict__ W2, const float* __restrict__ b1,
                          const float* __restrict__ b2, float* __restrict__ c){
  int gid = blockIdx.x*256 + threadIdx.x;      // e*DM + d
  int e = gid >> 9, d = gid & (DM-1);
  int fc = blockIdx.y;
  float acc = (fc == 0) ? b2[gid] : 0.f;
  const float* w  = W2 + (size_t)e*DFFN*DM + (size_t)fc*256*DM + d;
  const float* bb = b1 + e*DFFN + fc*256;
#pragma unroll 4
  for (int f = 0; f < 256; ++f) acc += fmaxf(bb[f], 0.f) * w[(size_t)f*DM];
  atomicAdd(&c[gid], acc);
}

// M[row=e*DFFN+f][p] = sum_d W2_0[e][f][d]*Wr1[d][p]   — one wave per row
__global__ void compute_M(const float* __restrict__ W2_0, const float* __restrict__ Wr1,
                          float* __restrict__ M, int nrows){
  int wv = threadIdx.x >> 6, lane = threadIdx.x & 63;
  int row = blockIdx.x*4 + wv;
  if (row >= nrows) return;
  const float* w = W2_0 + (size_t)row*DM + lane*8;
  float w8[8];
#pragma unroll
  for (int q = 0; q < 8; ++q) w8[q] = w[q];
  double acc[8] = {0,0,0,0,0,0,0,0};
#pragma unroll
  for (int q = 0; q < 8; ++q){
    const float* wr = Wr1 + (size_t)(lane*8 + q)*NE1;
#pragma unroll
    for (int p = 0; p < 8; ++p) acc[p] += (double)w8[q]*(double)wr[p];
  }
#pragma unroll
  for (int p = 0; p < 8; ++p) acc[p] = wave_sum_f64(acc[p]);
  if (lane == 0){
#pragma unroll
    for (int p = 0; p < 8; ++p) M[(size_t)row*8 + p] = (float)acc[p];
  }
}

__global__ void compute_cb_proj(const float* __restrict__ c0, const float* __restrict__ b2_0,
                                const float* __restrict__ Wr1, double* __restrict__ c0p,
                                double* __restrict__ b2p){
  int t = threadIdx.x;
  if (t >= NE0*NE1) return;
  int e = t >> 3, p = t & 7;
  double a = 0.0, b = 0.0;
  for (int d = 0; d < DM; ++d){
    double w = (double)Wr1[d*NE1 + p];
    a += (double)c0[e*DM + d]  * w;
    b += (double)b2_0[e*DM + d]* w;
  }
  c0p[t] = a; b2p[t] = b;
}

__global__ void prefix_offs(const int* __restrict__ counts, int NE, int* __restrict__ offs){
  if (threadIdx.x == 0){
    int s = 0;
    for (int e = 0; e < NE; ++e){ offs[e] = s; s += counts[e]; }
    offs[NE] = s;
  }
}

// ---------------- routers (no atomics — probs + top-2 idx; router0 also splits x) ----------------
__global__ void router0_kernel(const float* __restrict__ x, const float* __restrict__ Wr0,
                               float* __restrict__ probs0, int* __restrict__ idx0,
                               bf16* __restrict__ xhi, bf16* __restrict__ xlo){
  int wv = threadIdx.x >> 6, lane = threadIdx.x & 63;
  int t = blockIdx.x*4 + wv;
  const float* xr = x + (size_t)t*DM + lane*8;
  float xv[8];
#pragma unroll
  for (int i = 0; i < 8; ++i) xv[i] = xr[i];
  // fused split-convert: write hi/lo bf16 copies of x
  bf16x8 hv, lv;
#pragma unroll
  for (int i = 0; i < 8; ++i){
    bf16 h = (bf16)xv[i];
    hv[i] = h;
    lv[i] = (bf16)(xv[i] - (float)h);
  }
  *(bf16x8*)(xhi + (size_t)t*DM + lane*8) = hv;
  *(bf16x8*)(xlo + (size_t)t*DM + lane*8) = lv;

  double lg[NE0];
#pragma unroll
  for (int e = 0; e < NE0; ++e){
    double s = 0.0;
#pragma unroll
    for (int i = 0; i < 8; ++i) s += (double)xv[i] * (double)Wr0[(lane*8 + i)*NE0 + e];
    lg[e] = wave_sum_f64(s);
  }
  if (lane == 0){
    double m = lg[0];
#pragma unroll
    for (int e = 1; e < NE0; ++e) m = fmax(m, lg[e]);
    double den = 0.0, ex[NE0];
#pragma unroll
    for (int e = 0; e < NE0; ++e){ ex[e] = exp(lg[e] - m); den += ex[e]; }
    float pf[NE0];
#pragma unroll
    for (int e = 0; e < NE0; ++e){ pf[e] = (float)(ex[e]/den); probs0[t*NE0 + e] = pf[e]; }
    int e0 = 0;
#pragma unroll
    for (int e = 1; e < NE0; ++e) if (pf[e] > pf[e0]) e0 = e;
    int e1 = (e0 == 0) ? 1 : 0;
#pragma unroll
    for (int e = 0; e < NE0; ++e) if (e != e0 && pf[e] > pf[e1]) e1 = e;
    idx0[t*2 + 0] = e0; idx0[t*2 + 1] = e1;
  }
}

__global__ void router1_kernel(const float* __restrict__ proj, const float* __restrict__ probs0,
                               const int* __restrict__ idx0, const double* __restrict__ c0p,
                               const double* __restrict__ b2p, float* __restrict__ probs1,
                               int* __restrict__ idx1){
  int t = blockIdx.x*256 + threadIdx.x;
  float p0[NE0];
#pragma unroll
  for (int e = 0; e < NE0; ++e) p0[e] = probs0[t*NE0 + e];
  double lg[NE1];
#pragma unroll
  for (int p = 0; p < NE1; ++p){
    double s = 0.0;
#pragma unroll
    for (int e = 0; e < NE0; ++e) s += (double)p0[e] * c0p[e*NE1 + p];
    lg[p] = s;
  }
#pragma unroll
  for (int sl = 0; sl < 2; ++sl){
    int e = idx0[t*2 + sl];
    double pe = (double)p0[e];
    const float* pr = proj + ((size_t)(sl*TOK + t))*NE1;
#pragma unroll
    for (int p = 0; p < NE1; ++p) lg[p] += pe * ((double)pr[p] + b2p[e*NE1 + p] - c0p[e*NE1 + p]);
  }
  double m = lg[0];
#pragma unroll
  for (int p = 1; p < NE1; ++p) m = fmax(m, lg[p]);
  double den = 0.0, ex[NE1];
#pragma unroll
  for (int p = 0; p < NE1; ++p){ ex[p] = exp(lg[p] - m); den += ex[p]; }
  float pf[NE1];
#pragma unroll
  for (int p = 0; p < NE1; ++p){ pf[p] = (float)(ex[p]/den); probs1[t*NE1 + p] = pf[p]; }
  int e0 = 0;
#pragma unroll
  for (int p = 1; p < NE1; ++p) if (pf[p] > pf[e0]) e0 = p;
  int e1 = (e0 == 0) ? 1 : 0;
#pragma unroll
  for (int p = 0; p < NE1; ++p) if (p != e0 && pf[p] > pf[e1]) e1 = p;
  idx1[t*2 + 0] = e0; idx1[t*2 + 1] = e1;
}

// Build expert lists from idx with 3-level atomic aggregation.
// Also records posn[slot*TOK+t] = e*16384 + local_pos for the gather kernel.
__global__ void build_lists(const int* __restrict__ idx, int NE,
                            int* __restrict__ list, int* __restrict__ counts,
                            int* __restrict__ posn){
  __shared__ int lcnt[8];
  __shared__ int lbase[8];
  const int tid = threadIdx.x, lane = tid & 63;
  if (tid < NE) lcnt[tid] = 0;
  __syncthreads();
  const int g = blockIdx.x*1024 + tid;          // 0..2*TOK-1
  const int slot = g >> 13;                     // TOK = 8192
  const int t = g & (TOK-1);
  const int e = idx[t*2 + slot];
  int wbase = 0, rank = 0;
  for (int ee = 0; ee < NE; ++ee){
    unsigned long long m = __ballot(e == ee);
    if (e == ee){
      int leader = __builtin_ctzll(m);
      int b = 0;
      if (lane == leader) b = atomicAdd(&lcnt[ee], (int)__popcll(m));
      wbase = __shfl(b, leader, 64);
      rank  = (int)__popcll(m & ((1ull << lane) - 1ull));
    }
  }
  __syncthreads();
  if (tid < NE) lbase[tid] = atomicAdd(&counts[tid], lcnt[tid]);
  __syncthreads();
  const int p = lbase[e] + wbase + rank;
  list[e*TOK + p] = slot*TOK + t;
  posn[slot*TOK + t] = e*16384 + p;
}

// tgt[t][d] = sum_e probs[t][e]*c[e][d]
__global__ void init_combine(const float* __restrict__ probs, const float* __restrict__ c,
                             int NE, float* __restrict__ tgt){
  int gid = blockIdx.x*256 + threadIdx.x;
  int t = gid >> 9, d = gid & (DM-1);
  float v = 0.f;
  for (int e = 0; e < NE; ++e) v += probs[t*NE + e] * c[e*DM + d];
  tgt[gid] = v;
}

// Final combine (atomic-free path): v = init[t][d] + sum_slots g*(Y[r][d] + b2[e][d] - ce[e][d])
// Writes fp32 (outF) and/or bf16 (outB).
__global__ void gather_combine(const float* __restrict__ init, const float* __restrict__ Y,
                               const int* __restrict__ posn, const int* __restrict__ offs,
                               const float* __restrict__ probs, const float* __restrict__ b2,
                               const float* __restrict__ ce, int NE,
                               float* __restrict__ outF, bf16* __restrict__ outB){
  int gid = blockIdx.x*256 + threadIdx.x;       // one float4 per thread
  int t = gid >> 7, d4 = (gid & 127) << 2;      // DM/4 = 128
  f32x4 v = *(const f32x4*)(init + (size_t)t*DM + d4);
#pragma unroll
  for (int sl = 0; sl < 2; ++sl){
    int pv = posn[sl*TOK + t];
    int e = pv >> 14, p = pv & 16383;
    int r = offs[e] + p;
    float g = probs[t*NE + e];
    f32x4 y  = *(const f32x4*)(Y  + (size_t)r*DM + d4);
    f32x4 bb = *(const f32x4*)(b2 + (size_t)e*DM + d4);
    f32x4 cc = *(const f32x4*)(ce + (size_t)e*DM + d4);
#pragma unroll
    for (int q = 0; q < 4; ++q) v[q] += g*(y[q] + bb[q] - cc[q]);
  }
  if (outF) *(f32x4*)(outF + (size_t)t*DM + d4) = v;
  if (outB){
    bf16x4 hb;
#pragma unroll
    for (int q = 0; q < 4; ++q) hb[q] = (bf16)v[q];
    *(bf16x4*)(outB + (size_t)t*DM + d4) = hb;
  }
}

// proj[r][p] += sum_{f in chunk} (hi+lo)[rr][f] * Mproj[e][f0+f][p]   — wave per row, no atomics
__global__ void proj_from_h(const bf16* __restrict__ Hb, const bf16* __restrict__ Hlo,
                            int FC, int f0, const float* __restrict__ Mproj,
                            const int* __restrict__ list, const int* __restrict__ offs,
                            float* __restrict__ proj){
  int wv = threadIdx.x >> 6, lane = threadIdx.x & 63;
  int rr = blockIdx.x*4 + wv;
  if (rr >= offs[NE0]) return;
  int e = 0;
#pragma unroll
  for (int k = 1; k < NE0; ++k) if (rr >= offs[k]) e = k;
  int r = list[e*TOK + (rr - offs[e])];
  const bf16* hh = Hb  + (size_t)rr*FC;
  const bf16* hl = Hlo + (size_t)rr*FC;
  const float* Me = Mproj + ((size_t)e*DFFN + f0)*8;
  float acc[8] = {0,0,0,0,0,0,0,0};
  for (int c = 0; c < FC; c += 512){
    int fl = c + lane*8;
    if (fl < FC){
      bf16x8 a = *(const bf16x8*)(hh + fl);
      bf16x8 b = *(const bf16x8*)(hl + fl);
#pragma unroll
      for (int q = 0; q < 8; ++q){
        float hv = (float)a[q] + (float)b[q];
        const f32x4* mp = (const f32x4*)(Me + (size_t)(fl + q)*8);
        f32x4 m0 = mp[0], m1 = mp[1];
#pragma unroll
        for (int p = 0; p < 4; ++p){
          acc[p]   += hv * m0[p];
          acc[4+p] += hv * m1[p];
        }
      }
    }
  }
#pragma unroll
  for (int p = 0; p < 8; ++p) acc[p] = wave_sum_f32(acc[p]);
  if (lane == 0){
#pragma unroll
    for (int p = 0; p < 8; ++p) proj[(size_t)r*8 + p] += acc[p];
  }
}

// ---------------- GEMMs ----------------
// Counted-vmcnt double-buffered pipeline, BK=32 per step (R6-proven config).
// Per step: s_waitcnt vmcnt(N_newer) -> s_barrier -> ds_read+MFMA -> lgkmcnt(0) ->
// s_barrier -> stage(k+2). Loads never drained to 0 inside loop.

// FFN1: Hb[compact_row][n-f0] = relu(A[t]@W1[e][:,n] + b1[e][n])
// SPLIT=1: fused hi*hi + hi*lo + lo*hi per step (4 tiles staged/step), 48 MFMA/wave/step.
template<int SPLIT>
__global__ __launch_bounds__(256, 2) void gemm_ffn1(
    const bf16* __restrict__ Ahi, const bf16* __restrict__ Alo,
    const bf16* __restrict__ Bhi, const bf16* __restrict__ Blo,   // [E][DFFN][DM]
    const float* __restrict__ b1,
    const int* __restrict__ list, const int* __restrict__ counts,
    const int* __restrict__ offs,
    bf16* __restrict__ Hb, bf16* __restrict__ Hlo, int f0, int FC)
{
  constexpr int BUFE  = SPLIT ? 16384 : 8192;           // elems per staging buffer
  constexpr int SMEME = (2*BUFE > 17408) ? 2*BUFE : 17408;
  __shared__ alignas(16) bf16 smem[SMEME];

  const int e   = blockIdx.z;
  const int cnt = counts[e];
  // XCD-aware bijective remap (NCH==1 only): XCD keeps a fixed pair of weight n-tiles in L2.
  const int bx = blockIdx.x, by = blockIdx.y;
  int xl, yl;
  if (gridDim.y == 16){
    xl = ((by >> 1) << 3) + (bx >> 3);
    yl = ((bx & 7) << 1) + (by & 1);
  } else { xl = bx; yl = by; }
  const int m0 = xl * 128;
  if (m0 >= cnt) return;
  const int rbase = offs[e] + m0;
  const int n0  = yl * 128;                   // local within chunk
  const int ng0 = f0 + n0;

  const int tid  = threadIdx.x;
  const int lane = tid & 63, wv = tid >> 6;
  const int wm = wv >> 1, wn = wv & 1;
  const int quad = lane >> 4, l15 = lane & 15;
  const int* le = list + e*TOK;

  // staging geometry: 2 passes of 64 rows; 4 threads/row, 16B chunks swizzled
  const int strow = tid >> 2;                 // 0..63
  const int ch8   = (((tid & 3) ^ ((tid >> 3) & 3)) << 3);
  int growR[2];
#pragma unroll
  for (int p = 0; p < 2; ++p){
    int m = m0 + p*64 + strow;
    growR[p] = (m < cnt) ? (le[m] & (TOK-1)) : 0;
  }
  const bf16* Bh = Bhi + (size_t)e*DFFN*DM;
  const bf16* Bl = SPLIT ? (Blo + (size_t)e*DFFN*DM) : nullptr;

  f32x4 acc[4][4];
#pragma unroll
  for (int i = 0; i < 4; ++i)
#pragma unroll
    for (int j = 0; j < 4; ++j) acc[i][j] = (f32x4){0.f,0.f,0.f,0.f};

  // read offsets (elems within a tile of 4096)
  const int swzl = (l15 >> 1) & 3;
  int aPos[4], bPos[4];
#pragma unroll
  for (int i = 0; i < 4; ++i){
    aPos[i] = (wm*256 + (i*16 + l15)*4 + (quad ^ swzl)) * 8;
    bPos[i] = (wn*256 + (i*16 + l15)*4 + (quad ^ swzl)) * 8;
  }

  auto stage = [&](int ks, int buf){
    const int colo = (ks << 5) + ch8;
    bf16* dst = smem + buf*BUFE;
#pragma unroll
    for (int p = 0; p < 2; ++p){
      gload16(Ahi + (size_t)growR[p]*DM + colo,                  dst +         (p*256 + tid)*8);
      gload16(Bh  + (size_t)(ng0 + p*64 + strow)*DM + colo,      dst + 4096  + (p*256 + tid)*8);
      if (SPLIT){
        gload16(Alo + (size_t)growR[p]*DM + colo,                dst + 8192  + (p*256 + tid)*8);
        gload16(Bl  + (size_t)(ng0 + p*64 + strow)*DM + colo,    dst + 12288 + (p*256 + tid)*8);
      }
    }
  };

  constexpr int NIT = DM/32;                  // 16
  stage(0, 0);
  stage(1, 1);
  int cur = 0;
  for (int ks = 0; ks < NIT; ++ks){
    if (ks + 1 < NIT){
      if (SPLIT) asm volatile("s_waitcnt vmcnt(8)" ::: "memory");
      else       asm volatile("s_waitcnt vmcnt(4)" ::: "memory");
    } else {
      asm volatile("s_waitcnt vmcnt(0)" ::: "memory");
    }
    __builtin_amdgcn_sched_barrier(0);
    __builtin_amdgcn_s_barrier();
    __builtin_amdgcn_sched_barrier(0);
    const bf16* B0 = smem + cur*BUFE;
    bf16x8 ah[4], bh[4];
#pragma unroll
    for (int i = 0; i < 4; ++i){
      ah[i] = *(const bf16x8*)&B0[aPos[i]];
      bh[i] = *(const bf16x8*)&B0[4096 + bPos[i]];
    }
#pragma unroll
    for (int i = 0; i < 4; ++i)
#pragma unroll
      for (int j = 0; j < 4; ++j)
        acc[i][j] = __builtin_amdgcn_mfma_f32_16x16x32_bf16(ah[i], bh[j], acc[i][j], 0,0,0);
    if (SPLIT){
      bf16x8 t2[4];
#pragma unroll
      for (int i = 0; i < 4; ++i) t2[i] = *(const bf16x8*)&B0[12288 + bPos[i]];   // Blo
#pragma unroll
      for (int i = 0; i < 4; ++i)
#pragma unroll
        for (int j = 0; j < 4; ++j)
          acc[i][j] = __builtin_amdgcn_mfma_f32_16x16x32_bf16(ah[i], t2[j], acc[i][j], 0,0,0);
#pragma unroll
      for (int i = 0; i < 4; ++i) t2[i] = *(const bf16x8*)&B0[8192 + aPos[i]];    // Alo
#pragma unroll
      for (int i = 0; i < 4; ++i)
#pragma unroll
        for (int j = 0; j < 4; ++j)
          acc[i][j] = __builtin_amdgcn_mfma_f32_16x16x32_bf16(t2[i], bh[j], acc[i][j], 0,0,0);
    }
    asm volatile("s_waitcnt lgkmcnt(0)" ::: "memory");
    __builtin_amdgcn_sched_barrier(0);
    __builtin_amdgcn_s_barrier();
    __builtin_amdgcn_sched_barrier(0);
    if (ks + 2 < NIT) stage(ks + 2, cur);
    cur ^= 1;
  }

  // ---- epilogue: bias+relu, Cs transpose, vectorized stores ----
  float bjv[4];
#pragma unroll
  for (int j = 0; j < 4; ++j)
    bjv[j] = b1[e*DFFN + ng0 + wn*64 + j*16 + l15];

  bf16* Cs = smem;                                // 128 x 136 (padded)
#pragma unroll
  for (int i = 0; i < 4; ++i)
#pragma unroll
    for (int j = 0; j < 4; ++j)
#pragma unroll
      for (int reg = 0; reg < 4; ++reg){
        float h = fmaxf(acc[i][j][reg] + bjv[j], 0.f);
        Cs[(wm*64 + i*16 + quad*4 + reg)*136 + wn*64 + j*16 + l15] = (bf16)h;
      }
  __syncthreads();
  {
    const int srow = tid >> 1, shalf = (tid & 1) * 64;
    if (m0 + srow < cnt){
      bf16* dst = Hb + (size_t)(rbase + srow)*FC + n0 + shalf;
      const bf16* srcl = &Cs[srow*136 + shalf];
#pragma unroll
      for (int q = 0; q < 8; ++q)
        *(bf16x8*)(dst + q*8) = *(const bf16x8*)(srcl + q*8);
    }
  }
  if (SPLIT){
    __syncthreads();
#pragma unroll
    for (int i = 0; i < 4; ++i)
#pragma unroll
      for (int j = 0; j < 4; ++j)
#pragma unroll
        for (int reg = 0; reg < 4; ++reg){
          float h = fmaxf(acc[i][j][reg] + bjv[j], 0.f);
          bf16 hi = (bf16)h;
          Cs[(wm*64 + i*16 + quad*4 + reg)*136 + wn*64 + j*16 + l15] = (bf16)(h - (float)hi);
        }
    __syncthreads();
    const int srow = tid >> 1, shalf = (tid & 1) * 64;
    if (m0 + srow < cnt){
      bf16* dst = Hlo + (size_t)(rbase + srow)*FC + n0 + shalf;
      const bf16* srcl = &Cs[srow*136 + shalf];
#pragma unroll
      for (int q = 0; q < 8; ++q)
        *(bf16x8*)(dst + q*8) = *(const bf16x8*)(srcl + q*8);
    }
  }
}

// FFN2: Y[r][n] = Hb[row]@W2[e][f0:f0+FC,n]  (atomic-free path, NCH==1)
//   or: tgt[t][n] += probs[t][e]*( ... + b2-ce on chunk 0 )  (fallback, Y==nullptr)
__global__ __launch_bounds__(256, 3) void gemm_ffn2(
    const bf16* __restrict__ Hb, int FC, int f0,
    const bf16* __restrict__ Bt,                // [E][DM][DFFN]
    const float* __restrict__ b2, const float* __restrict__ ce,
    const float* __restrict__ probs, int NE,
    const int* __restrict__ list, const int* __restrict__ counts,
    const int* __restrict__ offs,
    float* __restrict__ tgt, int addBias, float* __restrict__ Y)
{
  __shared__ alignas(16) bf16 smem[16384];    // 2 buffers x 8192 elems (32 KiB)

  const int e   = blockIdx.z;
  const int cnt = counts[e];
  // XCD remap: grid (64,4,E); XCD c=bx%8 handles n-tile yl=c>>1 only.
  const int bx = blockIdx.x, by = blockIdx.y;
  const int xl = (bx >> 3) + (((bx & 1) + (by << 1)) << 3);
  const int yl = (bx & 7) >> 1;
  const int m0 = xl*128;
  if (m0 >= cnt) return;
  const int rbase = offs[e];
  const int n0  = yl*128;

  const int tid = threadIdx.x, lane = tid & 63, wv = tid >> 6;
  const int wm = wv >> 1, wn = wv & 1, quad = lane >> 4, l15 = lane & 15;
  const int* le = list + e*TOK;

  const int strow = tid >> 2;
  const int ch8   = (((tid & 3) ^ ((tid >> 3) & 3)) << 3);
  int growR[2];
#pragma unroll
  for (int p = 0; p < 2; ++p){
    int m = m0 + p*64 + strow;
    growR[p] = rbase + ((m < cnt) ? m : (cnt - 1));
  }
  const bf16* Be = Bt + (size_t)e*DM*DFFN;

  f32x4 acc[4][4];
#pragma unroll
  for (int i = 0; i < 4; ++i)
#pragma unroll
    for (int j = 0; j < 4; ++j) acc[i][j] = (f32x4){0.f,0.f,0.f,0.f};

  const int swzl = (l15 >> 1) & 3;
  int aPos[4], bPos[4];
#pragma unroll
  for (int i = 0; i < 4; ++i){
    aPos[i] = (wm*256 + (i*16 + l15)*4 + (quad ^ swzl)) * 8;
    bPos[i] = (wn*256 + (i*16 + l15)*4 + (quad ^ swzl)) * 8;
  }

  auto stage = [&](int ks, int buf){
    const int colo = (ks << 5) + ch8;
    bf16* dst = smem + buf*8192;
#pragma unroll
    for (int p = 0; p < 2; ++p){
      gload16(Hb + (size_t)growR[p]*FC + colo,                       dst +        (p*256 + tid)*8);
      gload16(Be + (size_t)(n0 + p*64 + strow)*DFFN + f0 + colo,     dst + 4096 + (p*256 + tid)*8);
    }
  };

  const int NIT = FC/32;
  stage(0, 0);
  stage(1, 1);
  int cur = 0;
  for (int ks = 0; ks < NIT; ++ks){
    if (ks + 1 < NIT) asm volatile("s_waitcnt vmcnt(4)" ::: "memory");
    else              asm volatile("s_waitcnt vmcnt(0)" ::: "memory");
    __builtin_amdgcn_sched_barrier(0);
    __builtin_amdgcn_s_barrier();
    __builtin_amdgcn_sched_barrier(0);
    const bf16* B0 = smem + cur*8192;
    bf16x8 a[4], b[4];
#pragma unroll
    for (int i = 0; i < 4; ++i){
      a[i] = *(const bf16x8*)&B0[aPos[i]];
      b[i] = *(const bf16x8*)&B0[4096 + bPos[i]];
    }
#pragma unroll
    for (int i = 0; i < 4; ++i)
#pragma unroll
      for (int j = 0; j < 4; ++j)
        acc[i][j] = __builtin_amdgcn_mfma_f32_16x16x32_bf16(a[i], b[j], acc[i][j], 0,0,0);
    asm volatile("s_waitcnt lgkmcnt(0)" ::: "memory");
    __builtin_amdgcn_sched_barrier(0);
    __builtin_amdgcn_s_barrier();
    __builtin_amdgcn_sched_barrier(0);
    if (ks + 2 < NIT) stage(ks + 2, cur);
    cur ^= 1;
  }
  if (Y){
    // atomic-free: plain stores to private compact-row buffer (16 lanes = 64B runs)
#pragma unroll
    for (int i = 0; i < 4; ++i){
#pragma unroll
      for (int reg = 0; reg < 4; ++reg){
        int m = m0 + wm*64 + i*16 + quad*4 + reg;
        if (m >= cnt) continue;
        float* yr = Y + (size_t)(rbase + m)*DM + n0;
#pragma unroll
        for (int j = 0; j < 4; ++j)
          yr[wn*64 + j*16 + l15] = acc[i][j][reg];
      }
    }
  } else {
#pragma unroll
    for (int i = 0; i < 4; ++i){
#pragma unroll
      for (int reg = 0; reg < 4; ++reg){
        int m = m0 + wm*64 + i*16 + quad*4 + reg;
        if (m >= cnt) continue;
        int r = le[m];
        int t = r & (TOK-1);
        float g = probs[t*NE + e];
#pragma unroll
        for (int j = 0; j < 4; ++j){
          int n = n0 + wn*64 + j*16 + l15;
          float v = acc[i][j][reg];
          if (addBias) v += b2[e*DM + n] - ce[e*DM + n];
          atomicAdd(&tgt[(size_t)t*DM + n], g*v);
        }
      }
    }
  }
}

// ---------------- launch ----------------
extern "C" void kernel_launch(void* const* d_in, const int* in_sizes, int n_in,
                              void* d_out, int out_size, void* d_ws, size_t ws_size,
                              hipStream_t stream)
{
  (void)in_sizes; (void)n_in; (void)out_size;
  const float* x    = (const float*)d_in[0];
  const float* Wr0  = (const float*)d_in[1];
  const float* W1_0 = (const float*)d_in[2];
  const float* b1_0 = (const float*)d_in[3];
  const float* W2_0 = (const float*)d_in[4];
  const float* b2_0 = (const float*)d_in[5];
  const float* Wr1  = (const float*)d_in[6];
  const float* W1_1 = (const float*)d_in[7];
  const float* b1_1 = (const float*)d_in[8];
  const float* W2_1 = (const float*)d_in[9];
  const float* b2_1 = (const float*)d_in[10];
  float* out = (float*)d_out;

  const size_t MB = (size_t)1 << 20;
  char* base = (char*)d_ws;

  bf16* xhi  = (bf16*)base;                 // 8 MB; phase B: h0b
  bf16* h0b  = (bf16*)base;
  bf16* xlo  = (bf16*)(base + 8*MB);        // 8 MB
  bf16* w10h = (bf16*)(base + 16*MB);       // 16 MB; phase B: w11h
  bf16* w10l = (bf16*)(base + 32*MB);       // 16 MB; phase B: w21h
  bf16* w11h = (bf16*)(base + 16*MB);
  bf16* w21h = (bf16*)(base + 32*MB);
  bf16* w20h = (bf16*)(base + 48*MB);       // 16 MB
  float* h0f = (float*)(base + 64*MB);      // 16 MB

  char* mp = base + 80*MB;                  // misc ~2.6 MB
  auto take = [&](size_t n) -> char* { char* p = mp; mp += (n + 255) & ~(size_t)255; return p; };
  float* probs0 = (float*)take((size_t)TOK*NE0*4);
  float* probs1 = (float*)take((size_t)TOK*NE1*4);
  int*   idx0   = (int*)  take((size_t)TOK*2*4);
  int*   idx1   = (int*)  take((size_t)TOK*2*4);
  int*   posn0  = (int*)  take((size_t)TOK*2*4);
  int*   posn1  = (int*)  take((size_t)TOK*2*4);
  int*   list0  = (int*)  take((size_t)NE0*TOK*4);
  int*   list1  = (int*)  take((size_t)NE1*TOK*4);
  int*   counts = (int*)  take(256);
  int*   offs0  = (int*)  take(256);
  int*   offs1  = (int*)  take(256);
  float* c0     = (float*)take((size_t)NE0*DM*4);
  float* c1     = (float*)take((size_t)NE1*DM*4);
  float* Mproj  = (float*)take((size_t)NE0*DFFN*NE1*4);
  double* c0p   = (double*)take(NE0*NE1*8);
  double* b2p   = (double*)take(NE0*NE1*8);
  float* proj   = (float*)take((size_t)2*TOK*NE1*4);

  const size_t fixed = 84*MB;
  int NCH;
  if      (ws_size >= fixed + 128*MB) NCH = 1;
  else if (ws_size >= fixed +  64*MB) NCH = 2;
  else if (ws_size >= fixed +  32*MB) NCH = 4;
  else if (ws_size >= fixed +  16*MB) NCH = 8;
  else return;  // workspace too small: clean validation failure, no fault
  const int FC = DFFN / NCH;
  const size_t chunkB = (size_t)2*TOK*FC*2;       // bytes per bf16 chunk buffer
  bf16* Hb   = (bf16*)(base + fixed);
  bf16* Hlo  = (bf16*)(base + fixed + chunkB);
  // Atomic-free ffn2 path (NCH==1 only): Y (32 MB fp32) reuses the Hlo region —
  // level 0: Hlo is dead after proj_from_h (stream-ordered before ffn2);
  // level 1: Hlo unused entirely.
  const bool useY = (NCH == 1);
  float* Ybuf = (float*)Hlo;

  hipMemsetAsync(counts, 0, 16*sizeof(int), stream);
  hipMemsetAsync(c0, 0, (size_t)(NE0+NE1)*DM*4, stream);   // c0,c1 contiguous
  hipMemsetAsync(proj, 0, (size_t)2*TOK*NE1*4, stream);

  // prep
  transpose_convert<<<dim3(DFFN/64, DM/64, NE0), 256, 0, stream>>>(W1_0, w10h, w10l, DM, DFFN);
  transpose_convert<<<dim3(DM/64, DFFN/64, NE0), 256, 0, stream>>>(W2_0, w20h, nullptr, DFFN, DM);
  compute_c<<<dim3(NE0*DM/256, 8), 256, 0, stream>>>(W2_0, b1_0, b2_0, c0);
  compute_c<<<dim3(NE1*DM/256, 8), 256, 0, stream>>>(W2_1, b1_1, b2_1, c1);
  compute_M<<<dim3(NE0*DFFN/4), 256, 0, stream>>>(W2_0, Wr1, Mproj, NE0*DFFN);
  compute_cb_proj<<<1, 64, 0, stream>>>(c0, b2_0, Wr1, c0p, b2p);

  // level 0
  router0_kernel<<<dim3(TOK/4), 256, 0, stream>>>(x, Wr0, probs0, idx0, xhi, xlo);
  build_lists<<<dim3(2*TOK/1024), 1024, 0, stream>>>(idx0, NE0, list0, counts, posn0);
  prefix_offs<<<1, 64, 0, stream>>>(counts, NE0, offs0);
  init_combine<<<dim3(TOK*DM/256), 256, 0, stream>>>(probs0, c0, NE0, h0f);
  for (int c = 0; c < NCH; ++c){
    gemm_ffn1<1><<<dim3(64, FC/128, NE0), 256, 0, stream>>>(
        xhi, xlo, w10h, w10l, b1_0, list0, counts, offs0, Hb, Hlo, c*FC, FC);
    proj_from_h<<<dim3(2*TOK/4), 256, 0, stream>>>(Hb, Hlo, FC, c*FC, Mproj,
                                                   list0, offs0, proj);
    gemm_ffn2<<<dim3(64, DM/128, NE0), 256, 0, stream>>>(
        Hb, FC, c*FC, w20h, b2_0, c0, probs0, NE0, list0, counts, offs0, h0f, (c == 0),
        useY ? Ybuf : nullptr);
  }

  // transition
  transpose_convert<<<dim3(DFFN/64, DM/64, NE1), 256, 0, stream>>>(W1_1, w11h, nullptr, DM, DFFN);
  transpose_convert<<<dim3(DM/64, DFFN/64, NE1), 256, 0, stream>>>(W2_1, w21h, nullptr, DFFN, DM);
  if (useY){
    gather_combine<<<dim3(TOK*DM/4/256), 256, 0, stream>>>(
        h0f, Ybuf, posn0, offs0, probs0, b2_0, c0, NE0, nullptr, h0b);
  } else {
    f32_to_bf16<<<dim3(TOK*DM/256), 256, 0, stream>>>(h0f, h0b, TOK*DM);
  }
  router1_kernel<<<dim3(TOK/256), 256, 0, stream>>>(proj, probs0, idx0, c0p, b2p,
                                                    probs1, idx1);
  build_lists<<<dim3(2*TOK/1024), 1024, 0, stream>>>(idx1, NE1, list1, counts + NE0, posn1);
  prefix_offs<<<1, 64, 0, stream>>>(counts + NE0, NE1, offs1);
  init_combine<<<dim3(TOK*DM/256), 256, 0, stream>>>(probs1, c1, NE1, out);

  // level 1
  for (int c = 0; c < NCH; ++c){
    gemm_ffn1<0><<<dim3(64, FC/128, NE1), 256, 0, stream>>>(
        h0b, nullptr, w11h, nullptr, b1_1, list1, counts + NE0, offs1,
        Hb, nullptr, c*FC, FC);
    gemm_ffn2<<<dim3(64, DM/128, NE1), 256, 0, stream>>>(
        Hb, FC, c*FC, w21h, b2_1, c1, probs1, NE1, list1, counts + NE0, offs1, out, (c == 0),
        useY ? Ybuf : nullptr);
  }
  if (useY){
    gather_combine<<<dim3(TOK*DM/4/256), 256, 0, stream>>>(
        out, Ybuf, posn1, offs1, probs1, b2_1, c1, NE1, out, nullptr);
  }
}

// Round 10
// 732.381 us; speedup vs baseline: 1.1990x; 1.1031x over previous
//
#include <hip/hip_runtime.h>
#include <hip/hip_bf16.h>
#include <math.h>

#define TOK   8192
#define DM    512
#define DFFN  2048
#define NE0   4
#define NE1   8

typedef __bf16 bf16;
typedef __bf16 bf16x4 __attribute__((ext_vector_type(4)));
typedef __bf16 bf16x8 __attribute__((ext_vector_type(8)));
typedef float  f32x4  __attribute__((ext_vector_type(4)));

__device__ __forceinline__ double wave_sum_f64(double v){
#pragma unroll
  for (int o = 32; o > 0; o >>= 1) v += __shfl_down(v, o, 64);
  return v;
}
__device__ __forceinline__ float wave_sum_f32(float v){
#pragma unroll
  for (int o = 32; o > 0; o >>= 1) v += __shfl_down(v, o, 64);
  return v;
}

// async global->LDS, 16B per lane; LDS dest = wave-uniform base + lane*16 (linear in tid).
__device__ __forceinline__ void gload16(const bf16* g, bf16* l){
  __builtin_amdgcn_global_load_lds(
      (const __attribute__((address_space(1))) void*)g,
      (__attribute__((address_space(3))) void*)l, 16, 0, 0);
}

// ---------------- prep kernels ----------------
__global__ void f32_to_bf16(const float* __restrict__ in, bf16* __restrict__ out, int n){
  int i = blockIdx.x*256 + threadIdx.x;
  if (i < n) out[i] = (bf16)in[i];
}

// in [E][K][N] fp32 -> out [E][N][K] bf16 (hi, optional lo)
__global__ void transpose_convert(const float* __restrict__ in, bf16* __restrict__ hi,
                                  bf16* __restrict__ lo, int K, int N){
  __shared__ float tile[64][65];
  int e  = blockIdx.z;
  int n0 = blockIdx.x*64, k0 = blockIdx.y*64;
  const float* src = in + (size_t)e*K*N;
  int c = threadIdx.x & 63, r4 = threadIdx.x >> 6;
#pragma unroll
  for (int i = 0; i < 16; ++i){
    int r = r4*16 + i;
    tile[r][c] = src[(size_t)(k0 + r)*N + n0 + c];
  }
  __syncthreads();
  bf16* dh = hi + (size_t)e*K*N;
  bf16* dl = lo ? (lo + (size_t)e*K*N) : nullptr;
#pragma unroll
  for (int i = 0; i < 16; ++i){
    int r = r4*16 + i;               // n-dim
    float v = tile[c][r];
    size_t o = (size_t)(n0 + r)*K + k0 + c;
    bf16 h = (bf16)v;
    dh[o] = h;
    if (dl) dl[o] = (bf16)(v - (float)h);
  }
}

// c[e][d] = b2[e][d] + sum_f relu(b1[e][f]) * W2[e][f][d]   — 32 f-chunks for latency hiding
__global__ void compute_c(const float* __restrict__ W2, const float* __restrict__ b1,
                          const float* __restrict__ b2, float* __restrict__ c){
  int gid = blockIdx.x*256 + threadIdx.x;      // e*DM + d
  int e = gid >> 9, d = gid & (DM-1);
  int fc = blockIdx.y;                          // 0..31, 64 f each
  float acc = (fc == 0) ? b2[gid] : 0.f;
  const float* w  = W2 + (size_t)e*DFFN*DM + (size_t)fc*64*DM + d;
  const float* bb = b1 + e*DFFN + fc*64;
#pragma unroll 4
  for (int f = 0; f < 64; ++f) acc += fmaxf(bb[f], 0.f) * w[(size_t)f*DM];
  atomicAdd(&c[gid], acc);
}

// M[row=e*DFFN+f][p] = sum_d W2_0[e][f][d]*Wr1[d][p]   — one wave per row
__global__ void compute_M(const float* __restrict__ W2_0, const float* __restrict__ Wr1,
                          float* __restrict__ M, int nrows){
  int wv = threadIdx.x >> 6, lane = threadIdx.x & 63;
  int row = blockIdx.x*4 + wv;
  if (row >= nrows) return;
  const float* w = W2_0 + (size_t)row*DM + lane*8;
  float w8[8];
#pragma unroll
  for (int q = 0; q < 8; ++q) w8[q] = w[q];
  double acc[8] = {0,0,0,0,0,0,0,0};
#pragma unroll
  for (int q = 0; q < 8; ++q){
    const float* wr = Wr1 + (size_t)(lane*8 + q)*NE1;
#pragma unroll
    for (int p = 0; p < 8; ++p) acc[p] += (double)w8[q]*(double)wr[p];
  }
#pragma unroll
  for (int p = 0; p < 8; ++p) acc[p] = wave_sum_f64(acc[p]);
  if (lane == 0){
#pragma unroll
    for (int p = 0; p < 8; ++p) M[(size_t)row*8 + p] = (float)acc[p];
  }
}

__global__ void compute_cb_proj(const float* __restrict__ c0, const float* __restrict__ b2_0,
                                const float* __restrict__ Wr1, double* __restrict__ c0p,
                                double* __restrict__ b2p){
  int t = threadIdx.x;
  if (t >= NE0*NE1) return;
  int e = t >> 3, p = t & 7;
  double a = 0.0, b = 0.0;
  for (int d = 0; d < DM; ++d){
    double w = (double)Wr1[d*NE1 + p];
    a += (double)c0[e*DM + d]  * w;
    b += (double)b2_0[e*DM + d]* w;
  }
  c0p[t] = a; b2p[t] = b;
}

__global__ void prefix_offs(const int* __restrict__ counts, int NE, int* __restrict__ offs){
  if (threadIdx.x == 0){
    int s = 0;
    for (int e = 0; e < NE; ++e){ offs[e] = s; s += counts[e]; }
    offs[NE] = s;
  }
}

// ---------------- routers (no atomics — probs + top-2 idx; router0 also splits x) ----------------
__global__ void router0_kernel(const float* __restrict__ x, const float* __restrict__ Wr0,
                               float* __restrict__ probs0, int* __restrict__ idx0,
                               bf16* __restrict__ xhi, bf16* __restrict__ xlo){
  int wv = threadIdx.x >> 6, lane = threadIdx.x & 63;
  int t = blockIdx.x*4 + wv;
  const float* xr = x + (size_t)t*DM + lane*8;
  float xv[8];
#pragma unroll
  for (int i = 0; i < 8; ++i) xv[i] = xr[i];
  // fused split-convert: write hi/lo bf16 copies of x
  bf16x8 hv, lv;
#pragma unroll
  for (int i = 0; i < 8; ++i){
    bf16 h = (bf16)xv[i];
    hv[i] = h;
    lv[i] = (bf16)(xv[i] - (float)h);
  }
  *(bf16x8*)(xhi + (size_t)t*DM + lane*8) = hv;
  *(bf16x8*)(xlo + (size_t)t*DM + lane*8) = lv;

  double lg[NE0];
#pragma unroll
  for (int e = 0; e < NE0; ++e){
    double s = 0.0;
#pragma unroll
    for (int i = 0; i < 8; ++i) s += (double)xv[i] * (double)Wr0[(lane*8 + i)*NE0 + e];
    lg[e] = wave_sum_f64(s);
  }
  if (lane == 0){
    double m = lg[0];
#pragma unroll
    for (int e = 1; e < NE0; ++e) m = fmax(m, lg[e]);
    double den = 0.0, ex[NE0];
#pragma unroll
    for (int e = 0; e < NE0; ++e){ ex[e] = exp(lg[e] - m); den += ex[e]; }
    float pf[NE0];
#pragma unroll
    for (int e = 0; e < NE0; ++e){ pf[e] = (float)(ex[e]/den); probs0[t*NE0 + e] = pf[e]; }
    int e0 = 0;
#pragma unroll
    for (int e = 1; e < NE0; ++e) if (pf[e] > pf[e0]) e0 = e;
    int e1 = (e0 == 0) ? 1 : 0;
#pragma unroll
    for (int e = 0; e < NE0; ++e) if (e != e0 && pf[e] > pf[e1]) e1 = e;
    idx0[t*2 + 0] = e0; idx0[t*2 + 1] = e1;
  }
}

__global__ void router1_kernel(const float* __restrict__ proj, const float* __restrict__ probs0,
                               const int* __restrict__ idx0, const double* __restrict__ c0p,
                               const double* __restrict__ b2p, float* __restrict__ probs1,
                               int* __restrict__ idx1){
  int t = blockIdx.x*256 + threadIdx.x;
  float p0[NE0];
#pragma unroll
  for (int e = 0; e < NE0; ++e) p0[e] = probs0[t*NE0 + e];
  double lg[NE1];
#pragma unroll
  for (int p = 0; p < NE1; ++p){
    double s = 0.0;
#pragma unroll
    for (int e = 0; e < NE0; ++e) s += (double)p0[e] * c0p[e*NE1 + p];
    lg[p] = s;
  }
#pragma unroll
  for (int sl = 0; sl < 2; ++sl){
    int e = idx0[t*2 + sl];
    double pe = (double)p0[e];
    const float* pr = proj + ((size_t)(sl*TOK + t))*NE1;
#pragma unroll
    for (int p = 0; p < NE1; ++p) lg[p] += pe * ((double)pr[p] + b2p[e*NE1 + p] - c0p[e*NE1 + p]);
  }
  double m = lg[0];
#pragma unroll
  for (int p = 1; p < NE1; ++p) m = fmax(m, lg[p]);
  double den = 0.0, ex[NE1];
#pragma unroll
  for (int p = 0; p < NE1; ++p){ ex[p] = exp(lg[p] - m); den += ex[p]; }
  float pf[NE1];
#pragma unroll
  for (int p = 0; p < NE1; ++p){ pf[p] = (float)(ex[p]/den); probs1[t*NE1 + p] = pf[p]; }
  int e0 = 0;
#pragma unroll
  for (int p = 1; p < NE1; ++p) if (pf[p] > pf[e0]) e0 = p;
  int e1 = (e0 == 0) ? 1 : 0;
#pragma unroll
  for (int p = 0; p < NE1; ++p) if (p != e0 && pf[p] > pf[e1]) e1 = p;
  idx1[t*2 + 0] = e0; idx1[t*2 + 1] = e1;
}

// Build expert lists from idx with 3-level atomic aggregation.
// Also records posn[slot*TOK+t] = e*16384 + local_pos for the gather kernel.
__global__ void build_lists(const int* __restrict__ idx, int NE,
                            int* __restrict__ list, int* __restrict__ counts,
                            int* __restrict__ posn){
  __shared__ int lcnt[8];
  __shared__ int lbase[8];
  const int tid = threadIdx.x, lane = tid & 63;
  if (tid < NE) lcnt[tid] = 0;
  __syncthreads();
  const int g = blockIdx.x*1024 + tid;          // 0..2*TOK-1
  const int slot = g >> 13;                     // TOK = 8192
  const int t = g & (TOK-1);
  const int e = idx[t*2 + slot];
  int wbase = 0, rank = 0;
  for (int ee = 0; ee < NE; ++ee){
    unsigned long long m = __ballot(e == ee);
    if (e == ee){
      int leader = __builtin_ctzll(m);
      int b = 0;
      if (lane == leader) b = atomicAdd(&lcnt[ee], (int)__popcll(m));
      wbase = __shfl(b, leader, 64);
      rank  = (int)__popcll(m & ((1ull << lane) - 1ull));
    }
  }
  __syncthreads();
  if (tid < NE) lbase[tid] = atomicAdd(&counts[tid], lcnt[tid]);
  __syncthreads();
  const int p = lbase[e] + wbase + rank;
  list[e*TOK + p] = slot*TOK + t;
  posn[slot*TOK + t] = e*16384 + p;
}

// tgt[t][d] = sum_e probs[t][e]*c[e][d]   (fallback path only)
__global__ void init_combine(const float* __restrict__ probs, const float* __restrict__ c,
                             int NE, float* __restrict__ tgt){
  int gid = blockIdx.x*256 + threadIdx.x;
  int t = gid >> 9, d = gid & (DM-1);
  float v = 0.f;
  for (int e = 0; e < NE; ++e) v += probs[t*NE + e] * c[e*DM + d];
  tgt[gid] = v;
}

// Final combine (atomic-free split-K path):
// v = sum_e probs[t][e]*ce[e][d] + sum_slots g*(Y[r][d] + Y2[r][d] + b2[e][d] - ce[e][d])
// (init term fused inline — ce is L2-hot, 8-16 KB). Writes fp32 and/or bf16.
__global__ void gather_combine(const float* __restrict__ Y,
                               const int* __restrict__ posn, const int* __restrict__ offs,
                               const float* __restrict__ probs, const float* __restrict__ b2,
                               const float* __restrict__ ce, int NE,
                               float* __restrict__ outF, bf16* __restrict__ outB){
  int gid = blockIdx.x*256 + threadIdx.x;       // one float4 per thread
  int t = gid >> 7, d4 = (gid & 127) << 2;      // DM/4 = 128
  const float* Y2 = Y + (size_t)16384*DM;
  f32x4 v = (f32x4){0.f,0.f,0.f,0.f};
  for (int e = 0; e < NE; ++e){
    float pe = probs[t*NE + e];
    f32x4 cc = *(const f32x4*)(ce + (size_t)e*DM + d4);
#pragma unroll
    for (int q = 0; q < 4; ++q) v[q] += pe*cc[q];
  }
#pragma unroll
  for (int sl = 0; sl < 2; ++sl){
    int pv = posn[sl*TOK + t];
    int e = pv >> 14, p = pv & 16383;
    int r = offs[e] + p;
    float g = probs[t*NE + e];
    f32x4 y1 = *(const f32x4*)(Y  + (size_t)r*DM + d4);
    f32x4 y2 = *(const f32x4*)(Y2 + (size_t)r*DM + d4);
    f32x4 bb = *(const f32x4*)(b2 + (size_t)e*DM + d4);
    f32x4 cc = *(const f32x4*)(ce + (size_t)e*DM + d4);
#pragma unroll
    for (int q = 0; q < 4; ++q) v[q] += g*(y1[q] + y2[q] + bb[q] - cc[q]);
  }
  if (outF) *(f32x4*)(outF + (size_t)t*DM + d4) = v;
  if (outB){
    bf16x4 hb;
#pragma unroll
    for (int q = 0; q < 4; ++q) hb[q] = (bf16)v[q];
    *(bf16x4*)(outB + (size_t)t*DM + d4) = hb;
  }
}

// proj[r][p] += sum_{f in chunk} (hi+lo)[rr][f] * Mproj[e][f0+f][p]   — wave per row, no atomics
__global__ void proj_from_h(const bf16* __restrict__ Hb, const bf16* __restrict__ Hlo,
                            int FC, int f0, const float* __restrict__ Mproj,
                            const int* __restrict__ list, const int* __restrict__ offs,
                            float* __restrict__ proj){
  int wv = threadIdx.x >> 6, lane = threadIdx.x & 63;
  int rr = blockIdx.x*4 + wv;
  if (rr >= offs[NE0]) return;
  int e = 0;
#pragma unroll
  for (int k = 1; k < NE0; ++k) if (rr >= offs[k]) e = k;
  int r = list[e*TOK + (rr - offs[e])];
  const bf16* hh = Hb  + (size_t)rr*FC;
  const bf16* hl = Hlo + (size_t)rr*FC;
  const float* Me = Mproj + ((size_t)e*DFFN + f0)*8;
  float acc[8] = {0,0,0,0,0,0,0,0};
  for (int c = 0; c < FC; c += 512){
    int fl = c + lane*8;
    if (fl < FC){
      bf16x8 a = *(const bf16x8*)(hh + fl);
      bf16x8 b = *(const bf16x8*)(hl + fl);
#pragma unroll
      for (int q = 0; q < 8; ++q){
        float hv = (float)a[q] + (float)b[q];
        const f32x4* mp = (const f32x4*)(Me + (size_t)(fl + q)*8);
        f32x4 m0 = mp[0], m1 = mp[1];
#pragma unroll
        for (int p = 0; p < 4; ++p){
          acc[p]   += hv * m0[p];
          acc[4+p] += hv * m1[p];
        }
      }
    }
  }
#pragma unroll
  for (int p = 0; p < 8; ++p) acc[p] = wave_sum_f32(acc[p]);
  if (lane == 0){
#pragma unroll
    for (int p = 0; p < 8; ++p) proj[(size_t)r*8 + p] += acc[p];
  }
}

// ---------------- GEMMs ----------------
// Counted-vmcnt double-buffered pipeline, BK=32 per step (R6-proven config).
// Per step: s_waitcnt vmcnt(N_newer) -> s_barrier -> ds_read+MFMA -> lgkmcnt(0) ->
// s_barrier -> stage(k+2). Loads never drained to 0 inside loop.

// FFN1: Hb[compact_row][n-f0] = relu(A[t]@W1[e][:,n] + b1[e][n])
// SPLIT=1: fused hi*hi + hi*lo + lo*hi per step (4 tiles staged/step), 48 MFMA/wave/step.
template<int SPLIT>
__global__ __launch_bounds__(256, 2) void gemm_ffn1(
    const bf16* __restrict__ Ahi, const bf16* __restrict__ Alo,
    const bf16* __restrict__ Bhi, const bf16* __restrict__ Blo,   // [E][DFFN][DM]
    const float* __restrict__ b1,
    const int* __restrict__ list, const int* __restrict__ counts,
    const int* __restrict__ offs,
    bf16* __restrict__ Hb, bf16* __restrict__ Hlo, int f0, int FC)
{
  constexpr int BUFE  = SPLIT ? 16384 : 8192;           // elems per staging buffer
  constexpr int SMEME = (2*BUFE > 17408) ? 2*BUFE : 17408;
  __shared__ alignas(16) bf16 smem[SMEME];

  const int e   = blockIdx.z;
  const int cnt = counts[e];
  // XCD-aware bijective remap (NCH==1 only): XCD keeps a fixed pair of weight n-tiles in L2.
  const int bx = blockIdx.x, by = blockIdx.y;
  int xl, yl;
  if (gridDim.y == 16){
    xl = ((by >> 1) << 3) + (bx >> 3);
    yl = ((bx & 7) << 1) + (by & 1);
  } else { xl = bx; yl = by; }
  const int m0 = xl * 128;
  if (m0 >= cnt) return;
  const int rbase = offs[e] + m0;
  const int n0  = yl * 128;                   // local within chunk
  const int ng0 = f0 + n0;

  const int tid  = threadIdx.x;
  const int lane = tid & 63, wv = tid >> 6;
  const int wm = wv >> 1, wn = wv & 1;
  const int quad = lane >> 4, l15 = lane & 15;
  const int* le = list + e*TOK;

  // staging geometry: 2 passes of 64 rows; 4 threads/row, 16B chunks swizzled
  const int strow = tid >> 2;                 // 0..63
  const int ch8   = (((tid & 3) ^ ((tid >> 3) & 3)) << 3);
  int growR[2];
#pragma unroll
  for (int p = 0; p < 2; ++p){
    int m = m0 + p*64 + strow;
    growR[p] = (m < cnt) ? (le[m] & (TOK-1)) : 0;
  }
  const bf16* Bh = Bhi + (size_t)e*DFFN*DM;
  const bf16* Bl = SPLIT ? (Blo + (size_t)e*DFFN*DM) : nullptr;

  f32x4 acc[4][4];
#pragma unroll
  for (int i = 0; i < 4; ++i)
#pragma unroll
    for (int j = 0; j < 4; ++j) acc[i][j] = (f32x4){0.f,0.f,0.f,0.f};

  // read offsets (elems within a tile of 4096)
  const int swzl = (l15 >> 1) & 3;
  int aPos[4], bPos[4];
#pragma unroll
  for (int i = 0; i < 4; ++i){
    aPos[i] = (wm*256 + (i*16 + l15)*4 + (quad ^ swzl)) * 8;
    bPos[i] = (wn*256 + (i*16 + l15)*4 + (quad ^ swzl)) * 8;
  }

  auto stage = [&](int ks, int buf){
    const int colo = (ks << 5) + ch8;
    bf16* dst = smem + buf*BUFE;
#pragma unroll
    for (int p = 0; p < 2; ++p){
      gload16(Ahi + (size_t)growR[p]*DM + colo,                  dst +         (p*256 + tid)*8);
      gload16(Bh  + (size_t)(ng0 + p*64 + strow)*DM + colo,      dst + 4096  + (p*256 + tid)*8);
      if (SPLIT){
        gload16(Alo + (size_t)growR[p]*DM + colo,                dst + 8192  + (p*256 + tid)*8);
        gload16(Bl  + (size_t)(ng0 + p*64 + strow)*DM + colo,    dst + 12288 + (p*256 + tid)*8);
      }
    }
  };

  constexpr int NIT = DM/32;                  // 16
  stage(0, 0);
  stage(1, 1);
  int cur = 0;
  for (int ks = 0; ks < NIT; ++ks){
    if (ks + 1 < NIT){
      if (SPLIT) asm volatile("s_waitcnt vmcnt(8)" ::: "memory");
      else       asm volatile("s_waitcnt vmcnt(4)" ::: "memory");
    } else {
      asm volatile("s_waitcnt vmcnt(0)" ::: "memory");
    }
    __builtin_amdgcn_sched_barrier(0);
    __builtin_amdgcn_s_barrier();
    __builtin_amdgcn_sched_barrier(0);
    const bf16* B0 = smem + cur*BUFE;
    bf16x8 ah[4], bh[4];
#pragma unroll
    for (int i = 0; i < 4; ++i){
      ah[i] = *(const bf16x8*)&B0[aPos[i]];
      bh[i] = *(const bf16x8*)&B0[4096 + bPos[i]];
    }
#pragma unroll
    for (int i = 0; i < 4; ++i)
#pragma unroll
      for (int j = 0; j < 4; ++j)
        acc[i][j] = __builtin_amdgcn_mfma_f32_16x16x32_bf16(ah[i], bh[j], acc[i][j], 0,0,0);
    if (SPLIT){
      bf16x8 t2[4];
#pragma unroll
      for (int i = 0; i < 4; ++i) t2[i] = *(const bf16x8*)&B0[12288 + bPos[i]];   // Blo
#pragma unroll
      for (int i = 0; i < 4; ++i)
#pragma unroll
        for (int j = 0; j < 4; ++j)
          acc[i][j] = __builtin_amdgcn_mfma_f32_16x16x32_bf16(ah[i], t2[j], acc[i][j], 0,0,0);
#pragma unroll
      for (int i = 0; i < 4; ++i) t2[i] = *(const bf16x8*)&B0[8192 + aPos[i]];    // Alo
#pragma unroll
      for (int i = 0; i < 4; ++i)
#pragma unroll
        for (int j = 0; j < 4; ++j)
          acc[i][j] = __builtin_amdgcn_mfma_f32_16x16x32_bf16(t2[i], bh[j], acc[i][j], 0,0,0);
    }
    asm volatile("s_waitcnt lgkmcnt(0)" ::: "memory");
    __builtin_amdgcn_sched_barrier(0);
    __builtin_amdgcn_s_barrier();
    __builtin_amdgcn_sched_barrier(0);
    if (ks + 2 < NIT) stage(ks + 2, cur);
    cur ^= 1;
  }

  // ---- epilogue: bias+relu, Cs transpose, vectorized stores ----
  float bjv[4];
#pragma unroll
  for (int j = 0; j < 4; ++j)
    bjv[j] = b1[e*DFFN + ng0 + wn*64 + j*16 + l15];

  bf16* Cs = smem;                                // 128 x 136 (padded)
#pragma unroll
  for (int i = 0; i < 4; ++i)
#pragma unroll
    for (int j = 0; j < 4; ++j)
#pragma unroll
      for (int reg = 0; reg < 4; ++reg){
        float h = fmaxf(acc[i][j][reg] + bjv[j], 0.f);
        Cs[(wm*64 + i*16 + quad*4 + reg)*136 + wn*64 + j*16 + l15] = (bf16)h;
      }
  __syncthreads();
  {
    const int srow = tid >> 1, shalf = (tid & 1) * 64;
    if (m0 + srow < cnt){
      bf16* dst = Hb + (size_t)(rbase + srow)*FC + n0 + shalf;
      const bf16* srcl = &Cs[srow*136 + shalf];
#pragma unroll
      for (int q = 0; q < 8; ++q)
        *(bf16x8*)(dst + q*8) = *(const bf16x8*)(srcl + q*8);
    }
  }
  if (SPLIT){
    __syncthreads();
#pragma unroll
    for (int i = 0; i < 4; ++i)
#pragma unroll
      for (int j = 0; j < 4; ++j)
#pragma unroll
        for (int reg = 0; reg < 4; ++reg){
          float h = fmaxf(acc[i][j][reg] + bjv[j], 0.f);
          bf16 hi = (bf16)h;
          Cs[(wm*64 + i*16 + quad*4 + reg)*136 + wn*64 + j*16 + l15] = (bf16)(h - (float)hi);
        }
    __syncthreads();
    const int srow = tid >> 1, shalf = (tid & 1) * 64;
    if (m0 + srow < cnt){
      bf16* dst = Hlo + (size_t)(rbase + srow)*FC + n0 + shalf;
      const bf16* srcl = &Cs[srow*136 + shalf];
#pragma unroll
      for (int q = 0; q < 8; ++q)
        *(bf16x8*)(dst + q*8) = *(const bf16x8*)(srcl + q*8);
    }
  }
}

// FFN2: atomic-free split-K path (Y != nullptr, NCH==1):
//   grid (64, 8, E); by&3 -> n-tile, by>>2 -> K-half; Y[kh][r][n] = Hb[row]@W2 half.
// Fallback (Y == nullptr): grid (64,4,E), atomic scatter with bias on chunk 0.
__global__ __launch_bounds__(256, 3) void gemm_ffn2(
    const bf16* __restrict__ Hb, int FC, int f0,
    const bf16* __restrict__ Bt,                // [E][DM][DFFN]
    const float* __restrict__ b2, const float* __restrict__ ce,
    const float* __restrict__ probs, int NE,
    const int* __restrict__ list, const int* __restrict__ counts,
    const int* __restrict__ offs,
    float* __restrict__ tgt, int addBias, float* __restrict__ Y)
{
  __shared__ alignas(16) bf16 smem[16384];    // 2 buffers x 8192 elems (32 KiB)

  const int e   = blockIdx.z;
  const int cnt = counts[e];
  const int bx = blockIdx.x, by = blockIdx.y;
  const int byn = Y ? (by & 3) : by;
  const int kh  = Y ? (by >> 2) : 0;
  // XCD remap: XCD c=bx%8 handles a fixed n-tile.
  const int xl = (bx >> 3) + (((bx & 1) + (byn << 1)) << 3);
  const int yl = (bx & 7) >> 1;
  const int m0 = xl*128;
  if (m0 >= cnt) return;
  const int rbase = offs[e];
  const int n0  = yl*128;
  const int FCk  = Y ? (FC >> 1) : FC;        // K columns this block covers
  const int kOff = kh * FCk;

  const int tid = threadIdx.x, lane = tid & 63, wv = tid >> 6;
  const int wm = wv >> 1, wn = wv & 1, quad = lane >> 4, l15 = lane & 15;
  const int* le = list + e*TOK;

  const int strow = tid >> 2;
  const int ch8   = (((tid & 3) ^ ((tid >> 3) & 3)) << 3);
  int growR[2];
#pragma unroll
  for (int p = 0; p < 2; ++p){
    int m = m0 + p*64 + strow;
    growR[p] = rbase + ((m < cnt) ? m : (cnt - 1));
  }
  const bf16* Be = Bt + (size_t)e*DM*DFFN;

  f32x4 acc[4][4];
#pragma unroll
  for (int i = 0; i < 4; ++i)
#pragma unroll
    for (int j = 0; j < 4; ++j) acc[i][j] = (f32x4){0.f,0.f,0.f,0.f};

  const int swzl = (l15 >> 1) & 3;
  int aPos[4], bPos[4];
#pragma unroll
  for (int i = 0; i < 4; ++i){
    aPos[i] = (wm*256 + (i*16 + l15)*4 + (quad ^ swzl)) * 8;
    bPos[i] = (wn*256 + (i*16 + l15)*4 + (quad ^ swzl)) * 8;
  }

  auto stage = [&](int ks, int buf){
    const int colo = kOff + (ks << 5) + ch8;
    bf16* dst = smem + buf*8192;
#pragma unroll
    for (int p = 0; p < 2; ++p){
      gload16(Hb + (size_t)growR[p]*FC + colo,                       dst +        (p*256 + tid)*8);
      gload16(Be + (size_t)(n0 + p*64 + strow)*DFFN + f0 + colo,     dst + 4096 + (p*256 + tid)*8);
    }
  };

  const int NIT = FCk/32;
  stage(0, 0);
  stage(1, 1);
  int cur = 0;
  for (int ks = 0; ks < NIT; ++ks){
    if (ks + 1 < NIT) asm volatile("s_waitcnt vmcnt(4)" ::: "memory");
    else              asm volatile("s_waitcnt vmcnt(0)" ::: "memory");
    __builtin_amdgcn_sched_barrier(0);
    __builtin_amdgcn_s_barrier();
    __builtin_amdgcn_sched_barrier(0);
    const bf16* B0 = smem + cur*8192;
    bf16x8 a[4], b[4];
#pragma unroll
    for (int i = 0; i < 4; ++i){
      a[i] = *(const bf16x8*)&B0[aPos[i]];
      b[i] = *(const bf16x8*)&B0[4096 + bPos[i]];
    }
#pragma unroll
    for (int i = 0; i < 4; ++i)
#pragma unroll
      for (int j = 0; j < 4; ++j)
        acc[i][j] = __builtin_amdgcn_mfma_f32_16x16x32_bf16(a[i], b[j], acc[i][j], 0,0,0);
    asm volatile("s_waitcnt lgkmcnt(0)" ::: "memory");
    __builtin_amdgcn_sched_barrier(0);
    __builtin_amdgcn_s_barrier();
    __builtin_amdgcn_sched_barrier(0);
    if (ks + 2 < NIT) stage(ks + 2, cur);
    cur ^= 1;
  }
  if (Y){
    float* Yb = Y + (size_t)kh*16384*DM;      // per-K-half private buffer
#pragma unroll
    for (int i = 0; i < 4; ++i){
#pragma unroll
      for (int reg = 0; reg < 4; ++reg){
        int m = m0 + wm*64 + i*16 + quad*4 + reg;
        if (m >= cnt) continue;
        float* yr = Yb + (size_t)(rbase + m)*DM + n0;
#pragma unroll
        for (int j = 0; j < 4; ++j)
          yr[wn*64 + j*16 + l15] = acc[i][j][reg];
      }
    }
  } else {
#pragma unroll
    for (int i = 0; i < 4; ++i){
#pragma unroll
      for (int reg = 0; reg < 4; ++reg){
        int m = m0 + wm*64 + i*16 + quad*4 + reg;
        if (m >= cnt) continue;
        int r = le[m];
        int t = r & (TOK-1);
        float g = probs[t*NE + e];
#pragma unroll
        for (int j = 0; j < 4; ++j){
          int n = n0 + wn*64 + j*16 + l15;
          float v = acc[i][j][reg];
          if (addBias) v += b2[e*DM + n] - ce[e*DM + n];
          atomicAdd(&tgt[(size_t)t*DM + n], g*v);
        }
      }
    }
  }
}

// ---------------- launch ----------------
extern "C" void kernel_launch(void* const* d_in, const int* in_sizes, int n_in,
                              void* d_out, int out_size, void* d_ws, size_t ws_size,
                              hipStream_t stream)
{
  (void)in_sizes; (void)n_in; (void)out_size;
  const float* x    = (const float*)d_in[0];
  const float* Wr0  = (const float*)d_in[1];
  const float* W1_0 = (const float*)d_in[2];
  const float* b1_0 = (const float*)d_in[3];
  const float* W2_0 = (const float*)d_in[4];
  const float* b2_0 = (const float*)d_in[5];
  const float* Wr1  = (const float*)d_in[6];
  const float* W1_1 = (const float*)d_in[7];
  const float* b1_1 = (const float*)d_in[8];
  const float* W2_1 = (const float*)d_in[9];
  const float* b2_1 = (const float*)d_in[10];
  float* out = (float*)d_out;

  const size_t MB = (size_t)1 << 20;
  char* base = (char*)d_ws;

  bf16* xhi  = (bf16*)base;                 // 8 MB; phase B: h0b
  bf16* h0b  = (bf16*)base;
  bf16* xlo  = (bf16*)(base + 8*MB);        // 8 MB
  bf16* w10h = (bf16*)(base + 16*MB);       // 16 MB; phase B: w11h
  bf16* w10l = (bf16*)(base + 32*MB);       // 16 MB; phase B: w21h
  bf16* w11h = (bf16*)(base + 16*MB);
  bf16* w21h = (bf16*)(base + 32*MB);
  bf16* w20h = (bf16*)(base + 48*MB);       // 16 MB
  float* h0f = (float*)(base + 64*MB);      // 16 MB (fallback path only)

  char* mp = base + 80*MB;                  // misc ~2.6 MB
  auto take = [&](size_t n) -> char* { char* p = mp; mp += (n + 255) & ~(size_t)255; return p; };
  float* probs0 = (float*)take((size_t)TOK*NE0*4);
  float* probs1 = (float*)take((size_t)TOK*NE1*4);
  int*   idx0   = (int*)  take((size_t)TOK*2*4);
  int*   idx1   = (int*)  take((size_t)TOK*2*4);
  int*   posn0  = (int*)  take((size_t)TOK*2*4);
  int*   posn1  = (int*)  take((size_t)TOK*2*4);
  int*   list0  = (int*)  take((size_t)NE0*TOK*4);
  int*   list1  = (int*)  take((size_t)NE1*TOK*4);
  int*   counts = (int*)  take(256);
  int*   offs0  = (int*)  take(256);
  int*   offs1  = (int*)  take(256);
  float* c0     = (float*)take((size_t)NE0*DM*4);
  float* c1     = (float*)take((size_t)NE1*DM*4);
  float* Mproj  = (float*)take((size_t)NE0*DFFN*NE1*4);
  double* c0p   = (double*)take(NE0*NE1*8);
  double* b2p   = (double*)take(NE0*NE1*8);
  float* proj   = (float*)take((size_t)2*TOK*NE1*4);

  const size_t fixed = 84*MB;
  int NCH;
  if      (ws_size >= fixed + 128*MB) NCH = 1;
  else if (ws_size >= fixed +  64*MB) NCH = 2;
  else if (ws_size >= fixed +  32*MB) NCH = 4;
  else if (ws_size >= fixed +  16*MB) NCH = 8;
  else return;  // workspace too small: clean validation failure, no fault
  const int FC = DFFN / NCH;
  const size_t chunkB = (size_t)2*TOK*FC*2;       // bytes per bf16 chunk buffer
  bf16* Hb   = (bf16*)(base + fixed);
  bf16* Hlo  = (bf16*)(base + fixed + chunkB);
  // Atomic-free split-K ffn2 (NCH==1 only): Y (2 x 32 MB fp32 halves) reuses the
  // 64 MB Hlo region — level 0: Hlo dead after proj_from_h (stream-ordered before
  // ffn2); level 1: Hlo unused entirely.
  const bool useY = (NCH == 1);
  float* Ybuf = (float*)Hlo;

  hipMemsetAsync(counts, 0, 16*sizeof(int), stream);
  hipMemsetAsync(c0, 0, (size_t)(NE0+NE1)*DM*4, stream);   // c0,c1 contiguous
  hipMemsetAsync(proj, 0, (size_t)2*TOK*NE1*4, stream);

  // prep
  transpose_convert<<<dim3(DFFN/64, DM/64, NE0), 256, 0, stream>>>(W1_0, w10h, w10l, DM, DFFN);
  transpose_convert<<<dim3(DM/64, DFFN/64, NE0), 256, 0, stream>>>(W2_0, w20h, nullptr, DFFN, DM);
  compute_c<<<dim3(NE0*DM/256, 32), 256, 0, stream>>>(W2_0, b1_0, b2_0, c0);
  compute_c<<<dim3(NE1*DM/256, 32), 256, 0, stream>>>(W2_1, b1_1, b2_1, c1);
  compute_M<<<dim3(NE0*DFFN/4), 256, 0, stream>>>(W2_0, Wr1, Mproj, NE0*DFFN);
  compute_cb_proj<<<1, 64, 0, stream>>>(c0, b2_0, Wr1, c0p, b2p);

  // level 0
  router0_kernel<<<dim3(TOK/4), 256, 0, stream>>>(x, Wr0, probs0, idx0, xhi, xlo);
  build_lists<<<dim3(2*TOK/1024), 1024, 0, stream>>>(idx0, NE0, list0, counts, posn0);
  prefix_offs<<<1, 64, 0, stream>>>(counts, NE0, offs0);
  if (!useY) init_combine<<<dim3(TOK*DM/256), 256, 0, stream>>>(probs0, c0, NE0, h0f);
  for (int c = 0; c < NCH; ++c){
    gemm_ffn1<1><<<dim3(64, FC/128, NE0), 256, 0, stream>>>(
        xhi, xlo, w10h, w10l, b1_0, list0, counts, offs0, Hb, Hlo, c*FC, FC);
    proj_from_h<<<dim3(2*TOK/4), 256, 0, stream>>>(Hb, Hlo, FC, c*FC, Mproj,
                                                   list0, offs0, proj);
    gemm_ffn2<<<dim3(64, useY ? 8 : 4, NE0), 256, 0, stream>>>(
        Hb, FC, c*FC, w20h, b2_0, c0, probs0, NE0, list0, counts, offs0, h0f, (c == 0),
        useY ? Ybuf : nullptr);
  }

  // transition
  transpose_convert<<<dim3(DFFN/64, DM/64, NE1), 256, 0, stream>>>(W1_1, w11h, nullptr, DM, DFFN);
  transpose_convert<<<dim3(DM/64, DFFN/64, NE1), 256, 0, stream>>>(W2_1, w21h, nullptr, DFFN, DM);
  if (useY){
    gather_combine<<<dim3(TOK*DM/4/256), 256, 0, stream>>>(
        Ybuf, posn0, offs0, probs0, b2_0, c0, NE0, nullptr, h0b);
  } else {
    f32_to_bf16<<<dim3(TOK*DM/256), 256, 0, stream>>>(h0f, h0b, TOK*DM);
  }
  router1_kernel<<<dim3(TOK/256), 256, 0, stream>>>(proj, probs0, idx0, c0p, b2p,
                                                    probs1, idx1);
  build_lists<<<dim3(2*TOK/1024), 1024, 0, stream>>>(idx1, NE1, list1, counts + NE0, posn1);
  prefix_offs<<<1, 64, 0, stream>>>(counts + NE0, NE1, offs1);
  if (!useY) init_combine<<<dim3(TOK*DM/256), 256, 0, stream>>>(probs1, c1, NE1, out);

  // level 1
  for (int c = 0; c < NCH; ++c){
    gemm_ffn1<0><<<dim3(64, FC/128, NE1), 256, 0, stream>>>(
        h0b, nullptr, w11h, nullptr, b1_1, list1, counts + NE0, offs1,
        Hb, nullptr, c*FC, FC);
    gemm_ffn2<<<dim3(64, useY ? 8 : 4, NE1), 256, 0, stream>>>(
        Hb, FC, c*FC, w21h, b2_1, c1, probs1, NE1, list1, counts + NE0, offs1, out, (c == 0),
        useY ? Ybuf : nullptr);
  }
  if (useY){
    gather_combine<<<dim3(TOK*DM/4/256), 256, 0, stream>>>(
        Ybuf, posn1, offs1, probs1, b2_1, c1, NE1, out, nullptr);
  }
}

// Round 11
// 708.347 us; speedup vs baseline: 1.2396x; 1.0339x over previous
//
#include <hip/hip_runtime.h>
#include <hip/hip_bf16.h>
#include <math.h>

#define TOK   8192
#define DM    512
#define DFFN  2048
#define NE0   4
#define NE1   8

typedef __bf16 bf16;
typedef __bf16 bf16x4 __attribute__((ext_vector_type(4)));
typedef __bf16 bf16x8 __attribute__((ext_vector_type(8)));
typedef float  f32x4  __attribute__((ext_vector_type(4)));

__device__ __forceinline__ double wave_sum_f64(double v){
#pragma unroll
  for (int o = 32; o > 0; o >>= 1) v += __shfl_down(v, o, 64);
  return v;
}
__device__ __forceinline__ float wave_sum_f32(float v){
#pragma unroll
  for (int o = 32; o > 0; o >>= 1) v += __shfl_down(v, o, 64);
  return v;
}

// async global->LDS, 16B per lane; LDS dest = wave-uniform base + lane*16 (linear in tid).
__device__ __forceinline__ void gload16(const bf16* g, bf16* l){
  __builtin_amdgcn_global_load_lds(
      (const __attribute__((address_space(1))) void*)g,
      (__attribute__((address_space(3))) void*)l, 16, 0, 0);
}

// ---------------- prep kernels ----------------
__global__ void f32_to_bf16(const float* __restrict__ in, bf16* __restrict__ out, int n){
  int i = blockIdx.x*256 + threadIdx.x;
  if (i < n) out[i] = (bf16)in[i];
}

// in [E][K][N] fp32 -> out [E][N][K] bf16 (hi, optional lo)
__global__ void transpose_convert(const float* __restrict__ in, bf16* __restrict__ hi,
                                  bf16* __restrict__ lo, int K, int N){
  __shared__ float tile[64][65];
  int e  = blockIdx.z;
  int n0 = blockIdx.x*64, k0 = blockIdx.y*64;
  const float* src = in + (size_t)e*K*N;
  int c = threadIdx.x & 63, r4 = threadIdx.x >> 6;
#pragma unroll
  for (int i = 0; i < 16; ++i){
    int r = r4*16 + i;
    tile[r][c] = src[(size_t)(k0 + r)*N + n0 + c];
  }
  __syncthreads();
  bf16* dh = hi + (size_t)e*K*N;
  bf16* dl = lo ? (lo + (size_t)e*K*N) : nullptr;
#pragma unroll
  for (int i = 0; i < 16; ++i){
    int r = r4*16 + i;               // n-dim
    float v = tile[c][r];
    size_t o = (size_t)(n0 + r)*K + k0 + c;
    bf16 h = (bf16)v;
    dh[o] = h;
    if (dl) dl[o] = (bf16)(v - (float)h);
  }
}

// c[e][d] = b2[e][d] + sum_f relu(b1[e][f]) * W2[e][f][d]   — 32 f-chunks for latency hiding
__global__ void compute_c(const float* __restrict__ W2, const float* __restrict__ b1,
                          const float* __restrict__ b2, float* __restrict__ c){
  int gid = blockIdx.x*256 + threadIdx.x;      // e*DM + d
  int e = gid >> 9, d = gid & (DM-1);
  int fc = blockIdx.y;                          // 0..31, 64 f each
  float acc = (fc == 0) ? b2[gid] : 0.f;
  const float* w  = W2 + (size_t)e*DFFN*DM + (size_t)fc*64*DM + d;
  const float* bb = b1 + e*DFFN + fc*64;
#pragma unroll 4
  for (int f = 0; f < 64; ++f) acc += fmaxf(bb[f], 0.f) * w[(size_t)f*DM];
  atomicAdd(&c[gid], acc);
}

// M[row=e*DFFN+f][p] = sum_d W2_0[e][f][d]*Wr1[d][p]   — one wave per row
__global__ void compute_M(const float* __restrict__ W2_0, const float* __restrict__ Wr1,
                          float* __restrict__ M, int nrows){
  int wv = threadIdx.x >> 6, lane = threadIdx.x & 63;
  int row = blockIdx.x*4 + wv;
  if (row >= nrows) return;
  const float* w = W2_0 + (size_t)row*DM + lane*8;
  float w8[8];
#pragma unroll
  for (int q = 0; q < 8; ++q) w8[q] = w[q];
  double acc[8] = {0,0,0,0,0,0,0,0};
#pragma unroll
  for (int q = 0; q < 8; ++q){
    const float* wr = Wr1 + (size_t)(lane*8 + q)*NE1;
#pragma unroll
    for (int p = 0; p < 8; ++p) acc[p] += (double)w8[q]*(double)wr[p];
  }
#pragma unroll
  for (int p = 0; p < 8; ++p) acc[p] = wave_sum_f64(acc[p]);
  if (lane == 0){
#pragma unroll
    for (int p = 0; p < 8; ++p) M[(size_t)row*8 + p] = (float)acc[p];
  }
}

// one wave per (e,p) pair — 32 waves total (was 1 block / 64 serial threads)
__global__ void compute_cb_proj(const float* __restrict__ c0, const float* __restrict__ b2_0,
                                const float* __restrict__ Wr1, double* __restrict__ c0p,
                                double* __restrict__ b2p){
  int wv = threadIdx.x >> 6, lane = threadIdx.x & 63;
  int pair = blockIdx.x*4 + wv;                 // 0..31
  if (pair >= NE0*NE1) return;
  int e = pair >> 3, p = pair & 7;
  double a = 0.0, b = 0.0;
#pragma unroll
  for (int q = 0; q < 8; ++q){
    int d = lane*8 + q;
    double w = (double)Wr1[d*NE1 + p];
    a += (double)c0[e*DM + d]  * w;
    b += (double)b2_0[e*DM + d]* w;
  }
  a = wave_sum_f64(a);
  b = wave_sum_f64(b);
  if (lane == 0){ c0p[pair] = a; b2p[pair] = b; }
}

// ---------------- routers (no atomics — probs + top-2 idx; router0 also splits x) ----------------
__global__ void router0_kernel(const float* __restrict__ x, const float* __restrict__ Wr0,
                               float* __restrict__ probs0, int* __restrict__ idx0,
                               bf16* __restrict__ xhi, bf16* __restrict__ xlo){
  int wv = threadIdx.x >> 6, lane = threadIdx.x & 63;
  int t = blockIdx.x*4 + wv;
  const float* xr = x + (size_t)t*DM + lane*8;
  float xv[8];
#pragma unroll
  for (int i = 0; i < 8; ++i) xv[i] = xr[i];
  // fused split-convert: write hi/lo bf16 copies of x
  bf16x8 hv, lv;
#pragma unroll
  for (int i = 0; i < 8; ++i){
    bf16 h = (bf16)xv[i];
    hv[i] = h;
    lv[i] = (bf16)(xv[i] - (float)h);
  }
  *(bf16x8*)(xhi + (size_t)t*DM + lane*8) = hv;
  *(bf16x8*)(xlo + (size_t)t*DM + lane*8) = lv;

  double lg[NE0];
#pragma unroll
  for (int e = 0; e < NE0; ++e){
    double s = 0.0;
#pragma unroll
    for (int i = 0; i < 8; ++i) s += (double)xv[i] * (double)Wr0[(lane*8 + i)*NE0 + e];
    lg[e] = wave_sum_f64(s);
  }
  if (lane == 0){
    double m = lg[0];
#pragma unroll
    for (int e = 1; e < NE0; ++e) m = fmax(m, lg[e]);
    double den = 0.0, ex[NE0];
#pragma unroll
    for (int e = 0; e < NE0; ++e){ ex[e] = exp(lg[e] - m); den += ex[e]; }
    float pf[NE0];
#pragma unroll
    for (int e = 0; e < NE0; ++e){ pf[e] = (float)(ex[e]/den); probs0[t*NE0 + e] = pf[e]; }
    int e0 = 0;
#pragma unroll
    for (int e = 1; e < NE0; ++e) if (pf[e] > pf[e0]) e0 = e;
    int e1 = (e0 == 0) ? 1 : 0;
#pragma unroll
    for (int e = 0; e < NE0; ++e) if (e != e0 && pf[e] > pf[e1]) e1 = e;
    idx0[t*2 + 0] = e0; idx0[t*2 + 1] = e1;
  }
}

__global__ void router1_kernel(const float* __restrict__ proj, const float* __restrict__ probs0,
                               const int* __restrict__ idx0, const double* __restrict__ c0p,
                               const double* __restrict__ b2p, float* __restrict__ probs1,
                               int* __restrict__ idx1){
  int t = blockIdx.x*256 + threadIdx.x;
  float p0[NE0];
#pragma unroll
  for (int e = 0; e < NE0; ++e) p0[e] = probs0[t*NE0 + e];
  double lg[NE1];
#pragma unroll
  for (int p = 0; p < NE1; ++p){
    double s = 0.0;
#pragma unroll
    for (int e = 0; e < NE0; ++e) s += (double)p0[e] * c0p[e*NE1 + p];
    lg[p] = s;
  }
#pragma unroll
  for (int sl = 0; sl < 2; ++sl){
    int e = idx0[t*2 + sl];
    double pe = (double)p0[e];
    const float* pr = proj + ((size_t)(sl*TOK + t))*NE1;
#pragma unroll
    for (int p = 0; p < NE1; ++p) lg[p] += pe * ((double)pr[p] + b2p[e*NE1 + p] - c0p[e*NE1 + p]);
  }
  double m = lg[0];
#pragma unroll
  for (int p = 1; p < NE1; ++p) m = fmax(m, lg[p]);
  double den = 0.0, ex[NE1];
#pragma unroll
  for (int p = 0; p < NE1; ++p){ ex[p] = exp(lg[p] - m); den += ex[p]; }
  float pf[NE1];
#pragma unroll
  for (int p = 0; p < NE1; ++p){ pf[p] = (float)(ex[p]/den); probs1[t*NE1 + p] = pf[p]; }
  int e0 = 0;
#pragma unroll
  for (int p = 1; p < NE1; ++p) if (pf[p] > pf[e0]) e0 = p;
  int e1 = (e0 == 0) ? 1 : 0;
#pragma unroll
  for (int p = 0; p < NE1; ++p) if (p != e0 && pf[p] > pf[e1]) e1 = p;
  idx1[t*2 + 0] = e0; idx1[t*2 + 1] = e1;
}

// Build expert lists from idx with 3-level atomic aggregation.
// Also records posn[slot*TOK+t] = e*16384 + local_pos for the gather kernel.
__global__ void build_lists(const int* __restrict__ idx, int NE,
                            int* __restrict__ list, int* __restrict__ counts,
                            int* __restrict__ posn){
  __shared__ int lcnt[8];
  __shared__ int lbase[8];
  const int tid = threadIdx.x, lane = tid & 63;
  if (tid < NE) lcnt[tid] = 0;
  __syncthreads();
  const int g = blockIdx.x*1024 + tid;          // 0..2*TOK-1
  const int slot = g >> 13;                     // TOK = 8192
  const int t = g & (TOK-1);
  const int e = idx[t*2 + slot];
  int wbase = 0, rank = 0;
  for (int ee = 0; ee < NE; ++ee){
    unsigned long long m = __ballot(e == ee);
    if (e == ee){
      int leader = __builtin_ctzll(m);
      int b = 0;
      if (lane == leader) b = atomicAdd(&lcnt[ee], (int)__popcll(m));
      wbase = __shfl(b, leader, 64);
      rank  = (int)__popcll(m & ((1ull << lane) - 1ull));
    }
  }
  __syncthreads();
  if (tid < NE) lbase[tid] = atomicAdd(&counts[tid], lcnt[tid]);
  __syncthreads();
  const int p = lbase[e] + wbase + rank;
  list[e*TOK + p] = slot*TOK + t;
  posn[slot*TOK + t] = e*16384 + p;
}

// tgt[t][d] = sum_e probs[t][e]*c[e][d]   (fallback path only)
__global__ void init_combine(const float* __restrict__ probs, const float* __restrict__ c,
                             int NE, float* __restrict__ tgt){
  int gid = blockIdx.x*256 + threadIdx.x;
  int t = gid >> 9, d = gid & (DM-1);
  float v = 0.f;
  for (int e = 0; e < NE; ++e) v += probs[t*NE + e] * c[e*DM + d];
  tgt[gid] = v;
}

// Final combine (atomic-free split-K path):
// v = sum_e probs[t][e]*ce[e][d] + sum_slots g*(Y[r][d] + Y2[r][d] + b2[e][d] - ce[e][d])
// offsets computed inline from counts (<=8 L2-hot scalar loads).
__global__ void gather_combine(const float* __restrict__ Y,
                               const int* __restrict__ posn, const int* __restrict__ counts,
                               const float* __restrict__ probs, const float* __restrict__ b2,
                               const float* __restrict__ ce, int NE,
                               float* __restrict__ outF, bf16* __restrict__ outB){
  int gid = blockIdx.x*256 + threadIdx.x;       // one float4 per thread
  int t = gid >> 7, d4 = (gid & 127) << 2;      // DM/4 = 128
  int offs[9];
  offs[0] = 0;
  for (int e = 0; e < NE; ++e) offs[e+1] = offs[e] + counts[e];
  const float* Y2 = Y + (size_t)16384*DM;
  f32x4 v = (f32x4){0.f,0.f,0.f,0.f};
  for (int e = 0; e < NE; ++e){
    float pe = probs[t*NE + e];
    f32x4 cc = *(const f32x4*)(ce + (size_t)e*DM + d4);
#pragma unroll
    for (int q = 0; q < 4; ++q) v[q] += pe*cc[q];
  }
#pragma unroll
  for (int sl = 0; sl < 2; ++sl){
    int pv = posn[sl*TOK + t];
    int e = pv >> 14, p = pv & 16383;
    int r = offs[e] + p;
    float g = probs[t*NE + e];
    f32x4 y1 = *(const f32x4*)(Y  + (size_t)r*DM + d4);
    f32x4 y2 = *(const f32x4*)(Y2 + (size_t)r*DM + d4);
    f32x4 bb = *(const f32x4*)(b2 + (size_t)e*DM + d4);
    f32x4 cc = *(const f32x4*)(ce + (size_t)e*DM + d4);
#pragma unroll
    for (int q = 0; q < 4; ++q) v[q] += g*(y1[q] + y2[q] + bb[q] - cc[q]);
  }
  if (outF) *(f32x4*)(outF + (size_t)t*DM + d4) = v;
  if (outB){
    bf16x4 hb;
#pragma unroll
    for (int q = 0; q < 4; ++q) hb[q] = (bf16)v[q];
    *(bf16x4*)(outB + (size_t)t*DM + d4) = hb;
  }
}

// proj[r][p] = / += sum_{f in chunk} (hi+lo)[rr][f] * Mproj[e][f0+f][p]
// f0==0 -> plain store (no memset needed); offsets inline from counts.
__global__ void proj_from_h(const bf16* __restrict__ Hb, const bf16* __restrict__ Hlo,
                            int FC, int f0, const float* __restrict__ Mproj,
                            const int* __restrict__ list, const int* __restrict__ counts,
                            float* __restrict__ proj){
  int wv = threadIdx.x >> 6, lane = threadIdx.x & 63;
  int rr = blockIdx.x*4 + wv;
  int offs[NE0+1];
  offs[0] = 0;
#pragma unroll
  for (int k = 0; k < NE0; ++k) offs[k+1] = offs[k] + counts[k];
  if (rr >= offs[NE0]) return;
  int e = 0;
#pragma unroll
  for (int k = 1; k < NE0; ++k) if (rr >= offs[k]) e = k;
  int r = list[e*TOK + (rr - offs[e])];
  const bf16* hh = Hb  + (size_t)rr*FC;
  const bf16* hl = Hlo + (size_t)rr*FC;
  const float* Me = Mproj + ((size_t)e*DFFN + f0)*8;
  float acc[8] = {0,0,0,0,0,0,0,0};
  for (int c = 0; c < FC; c += 512){
    int fl = c + lane*8;
    if (fl < FC){
      bf16x8 a = *(const bf16x8*)(hh + fl);
      bf16x8 b = *(const bf16x8*)(hl + fl);
#pragma unroll
      for (int q = 0; q < 8; ++q){
        float hv = (float)a[q] + (float)b[q];
        const f32x4* mp = (const f32x4*)(Me + (size_t)(fl + q)*8);
        f32x4 m0 = mp[0], m1 = mp[1];
#pragma unroll
        for (int p = 0; p < 4; ++p){
          acc[p]   += hv * m0[p];
          acc[4+p] += hv * m1[p];
        }
      }
    }
  }
#pragma unroll
  for (int p = 0; p < 8; ++p) acc[p] = wave_sum_f32(acc[p]);
  if (lane == 0){
    if (f0 == 0){
#pragma unroll
      for (int p = 0; p < 8; ++p) proj[(size_t)r*8 + p] = acc[p];
    } else {
#pragma unroll
      for (int p = 0; p < 8; ++p) proj[(size_t)r*8 + p] += acc[p];
    }
  }
}

// ---------------- GEMMs ----------------
// Counted-vmcnt double-buffered pipeline, BK=32 per step (R6-proven config).
// Per step: s_waitcnt vmcnt(N_newer) -> s_barrier -> ds_read+MFMA -> lgkmcnt(0) ->
// s_barrier -> stage(k+2). Loads never drained to 0 inside loop.

// FFN1: Hb[compact_row][n-f0] = relu(A[t]@W1[e][:,n] + b1[e][n])
// SPLIT=1: fused hi*hi + hi*lo + lo*hi per step (4 tiles staged/step), 48 MFMA/wave/step.
template<int SPLIT>
__global__ __launch_bounds__(256, 2) void gemm_ffn1(
    const bf16* __restrict__ Ahi, const bf16* __restrict__ Alo,
    const bf16* __restrict__ Bhi, const bf16* __restrict__ Blo,   // [E][DFFN][DM]
    const float* __restrict__ b1,
    const int* __restrict__ list, const int* __restrict__ counts,
    bf16* __restrict__ Hb, bf16* __restrict__ Hlo, int f0, int FC)
{
  constexpr int BUFE  = SPLIT ? 16384 : 8192;           // elems per staging buffer
  constexpr int SMEME = (2*BUFE > 17408) ? 2*BUFE : 17408;
  __shared__ alignas(16) bf16 smem[SMEME];

  const int e   = blockIdx.z;
  const int cnt = counts[e];
  int offe = 0;
  for (int k = 0; k < e; ++k) offe += counts[k];       // inline prefix (wave-uniform)
  // XCD-aware bijective remap (NCH==1 only): XCD keeps a fixed pair of weight n-tiles in L2.
  const int bx = blockIdx.x, by = blockIdx.y;
  int xl, yl;
  if (gridDim.y == 16){
    xl = ((by >> 1) << 3) + (bx >> 3);
    yl = ((bx & 7) << 1) + (by & 1);
  } else { xl = bx; yl = by; }
  const int m0 = xl * 128;
  if (m0 >= cnt) return;
  const int rbase = offe + m0;
  const int n0  = yl * 128;                   // local within chunk
  const int ng0 = f0 + n0;

  const int tid  = threadIdx.x;
  const int lane = tid & 63, wv = tid >> 6;
  const int wm = wv >> 1, wn = wv & 1;
  const int quad = lane >> 4, l15 = lane & 15;
  const int* le = list + e*TOK;

  // staging geometry: 2 passes of 64 rows; 4 threads/row, 16B chunks swizzled
  const int strow = tid >> 2;                 // 0..63
  const int ch8   = (((tid & 3) ^ ((tid >> 3) & 3)) << 3);
  int growR[2];
#pragma unroll
  for (int p = 0; p < 2; ++p){
    int m = m0 + p*64 + strow;
    growR[p] = (m < cnt) ? (le[m] & (TOK-1)) : 0;
  }
  const bf16* Bh = Bhi + (size_t)e*DFFN*DM;
  const bf16* Bl = SPLIT ? (Blo + (size_t)e*DFFN*DM) : nullptr;

  f32x4 acc[4][4];
#pragma unroll
  for (int i = 0; i < 4; ++i)
#pragma unroll
    for (int j = 0; j < 4; ++j) acc[i][j] = (f32x4){0.f,0.f,0.f,0.f};

  // read offsets (elems within a tile of 4096)
  const int swzl = (l15 >> 1) & 3;
  int aPos[4], bPos[4];
#pragma unroll
  for (int i = 0; i < 4; ++i){
    aPos[i] = (wm*256 + (i*16 + l15)*4 + (quad ^ swzl)) * 8;
    bPos[i] = (wn*256 + (i*16 + l15)*4 + (quad ^ swzl)) * 8;
  }

  auto stage = [&](int ks, int buf){
    const int colo = (ks << 5) + ch8;
    bf16* dst = smem + buf*BUFE;
#pragma unroll
    for (int p = 0; p < 2; ++p){
      gload16(Ahi + (size_t)growR[p]*DM + colo,                  dst +         (p*256 + tid)*8);
      gload16(Bh  + (size_t)(ng0 + p*64 + strow)*DM + colo,      dst + 4096  + (p*256 + tid)*8);
      if (SPLIT){
        gload16(Alo + (size_t)growR[p]*DM + colo,                dst + 8192  + (p*256 + tid)*8);
        gload16(Bl  + (size_t)(ng0 + p*64 + strow)*DM + colo,    dst + 12288 + (p*256 + tid)*8);
      }
    }
  };

  constexpr int NIT = DM/32;                  // 16
  stage(0, 0);
  stage(1, 1);
  int cur = 0;
  for (int ks = 0; ks < NIT; ++ks){
    if (ks + 1 < NIT){
      if (SPLIT) asm volatile("s_waitcnt vmcnt(8)" ::: "memory");
      else       asm volatile("s_waitcnt vmcnt(4)" ::: "memory");
    } else {
      asm volatile("s_waitcnt vmcnt(0)" ::: "memory");
    }
    __builtin_amdgcn_sched_barrier(0);
    __builtin_amdgcn_s_barrier();
    __builtin_amdgcn_sched_barrier(0);
    const bf16* B0 = smem + cur*BUFE;
    bf16x8 ah[4], bh[4];
#pragma unroll
    for (int i = 0; i < 4; ++i){
      ah[i] = *(const bf16x8*)&B0[aPos[i]];
      bh[i] = *(const bf16x8*)&B0[4096 + bPos[i]];
    }
#pragma unroll
    for (int i = 0; i < 4; ++i)
#pragma unroll
      for (int j = 0; j < 4; ++j)
        acc[i][j] = __builtin_amdgcn_mfma_f32_16x16x32_bf16(ah[i], bh[j], acc[i][j], 0,0,0);
    if (SPLIT){
      bf16x8 t2[4];
#pragma unroll
      for (int i = 0; i < 4; ++i) t2[i] = *(const bf16x8*)&B0[12288 + bPos[i]];   // Blo
#pragma unroll
      for (int i = 0; i < 4; ++i)
#pragma unroll
        for (int j = 0; j < 4; ++j)
          acc[i][j] = __builtin_amdgcn_mfma_f32_16x16x32_bf16(ah[i], t2[j], acc[i][j], 0,0,0);
#pragma unroll
      for (int i = 0; i < 4; ++i) t2[i] = *(const bf16x8*)&B0[8192 + aPos[i]];    // Alo
#pragma unroll
      for (int i = 0; i < 4; ++i)
#pragma unroll
        for (int j = 0; j < 4; ++j)
          acc[i][j] = __builtin_amdgcn_mfma_f32_16x16x32_bf16(t2[i], bh[j], acc[i][j], 0,0,0);
    }
    asm volatile("s_waitcnt lgkmcnt(0)" ::: "memory");
    __builtin_amdgcn_sched_barrier(0);
    __builtin_amdgcn_s_barrier();
    __builtin_amdgcn_sched_barrier(0);
    if (ks + 2 < NIT) stage(ks + 2, cur);
    cur ^= 1;
  }

  // ---- epilogue: bias+relu, Cs transpose, vectorized stores ----
  float bjv[4];
#pragma unroll
  for (int j = 0; j < 4; ++j)
    bjv[j] = b1[e*DFFN + ng0 + wn*64 + j*16 + l15];

  bf16* Cs = smem;                                // 128 x 136 (padded)
#pragma unroll
  for (int i = 0; i < 4; ++i)
#pragma unroll
    for (int j = 0; j < 4; ++j)
#pragma unroll
      for (int reg = 0; reg < 4; ++reg){
        float h = fmaxf(acc[i][j][reg] + bjv[j], 0.f);
        Cs[(wm*64 + i*16 + quad*4 + reg)*136 + wn*64 + j*16 + l15] = (bf16)h;
      }
  __syncthreads();
  {
    const int srow = tid >> 1, shalf = (tid & 1) * 64;
    if (m0 + srow < cnt){
      bf16* dst = Hb + (size_t)(rbase + srow)*FC + n0 + shalf;
      const bf16* srcl = &Cs[srow*136 + shalf];
#pragma unroll
      for (int q = 0; q < 8; ++q)
        *(bf16x8*)(dst + q*8) = *(const bf16x8*)(srcl + q*8);
    }
  }
  if (SPLIT){
    __syncthreads();
#pragma unroll
    for (int i = 0; i < 4; ++i)
#pragma unroll
      for (int j = 0; j < 4; ++j)
#pragma unroll
        for (int reg = 0; reg < 4; ++reg){
          float h = fmaxf(acc[i][j][reg] + bjv[j], 0.f);
          bf16 hi = (bf16)h;
          Cs[(wm*64 + i*16 + quad*4 + reg)*136 + wn*64 + j*16 + l15] = (bf16)(h - (float)hi);
        }
    __syncthreads();
    const int srow = tid >> 1, shalf = (tid & 1) * 64;
    if (m0 + srow < cnt){
      bf16* dst = Hlo + (size_t)(rbase + srow)*FC + n0 + shalf;
      const bf16* srcl = &Cs[srow*136 + shalf];
#pragma unroll
      for (int q = 0; q < 8; ++q)
        *(bf16x8*)(dst + q*8) = *(const bf16x8*)(srcl + q*8);
    }
  }
}

// FFN2: atomic-free split-K path (Y != nullptr, NCH==1):
//   grid (64, 8, E); by&3 -> n-tile, by>>2 -> K-half; Y[kh][r][n] = Hb[row]@W2 half.
// Fallback (Y == nullptr): grid (64,4,E), atomic scatter with bias on chunk 0.
__global__ __launch_bounds__(256, 3) void gemm_ffn2(
    const bf16* __restrict__ Hb, int FC, int f0,
    const bf16* __restrict__ Bt,                // [E][DM][DFFN]
    const float* __restrict__ b2, const float* __restrict__ ce,
    const float* __restrict__ probs, int NE,
    const int* __restrict__ list, const int* __restrict__ counts,
    float* __restrict__ tgt, int addBias, float* __restrict__ Y)
{
  __shared__ alignas(16) bf16 smem[16384];    // 2 buffers x 8192 elems (32 KiB)

  const int e   = blockIdx.z;
  const int cnt = counts[e];
  int rbase = 0;
  for (int k = 0; k < e; ++k) rbase += counts[k];      // inline prefix
  const int bx = blockIdx.x, by = blockIdx.y;
  const int byn = Y ? (by & 3) : by;
  const int kh  = Y ? (by >> 2) : 0;
  // XCD remap: XCD c=bx%8 handles a fixed n-tile.
  const int xl = (bx >> 3) + (((bx & 1) + (byn << 1)) << 3);
  const int yl = (bx & 7) >> 1;
  const int m0 = xl*128;
  if (m0 >= cnt) return;
  const int n0  = yl*128;
  const int FCk  = Y ? (FC >> 1) : FC;        // K columns this block covers
  const int kOff = kh * FCk;

  const int tid = threadIdx.x, lane = tid & 63, wv = tid >> 6;
  const int wm = wv >> 1, wn = wv & 1, quad = lane >> 4, l15 = lane & 15;
  const int* le = list + e*TOK;

  const int strow = tid >> 2;
  const int ch8   = (((tid & 3) ^ ((tid >> 3) & 3)) << 3);
  int growR[2];
#pragma unroll
  for (int p = 0; p < 2; ++p){
    int m = m0 + p*64 + strow;
    growR[p] = rbase + ((m < cnt) ? m : (cnt - 1));
  }
  const bf16* Be = Bt + (size_t)e*DM*DFFN;

  f32x4 acc[4][4];
#pragma unroll
  for (int i = 0; i < 4; ++i)
#pragma unroll
    for (int j = 0; j < 4; ++j) acc[i][j] = (f32x4){0.f,0.f,0.f,0.f};

  const int swzl = (l15 >> 1) & 3;
  int aPos[4], bPos[4];
#pragma unroll
  for (int i = 0; i < 4; ++i){
    aPos[i] = (wm*256 + (i*16 + l15)*4 + (quad ^ swzl)) * 8;
    bPos[i] = (wn*256 + (i*16 + l15)*4 + (quad ^ swzl)) * 8;
  }

  auto stage = [&](int ks, int buf){
    const int colo = kOff + (ks << 5) + ch8;
    bf16* dst = smem + buf*8192;
#pragma unroll
    for (int p = 0; p < 2; ++p){
      gload16(Hb + (size_t)growR[p]*FC + colo,                       dst +        (p*256 + tid)*8);
      gload16(Be + (size_t)(n0 + p*64 + strow)*DFFN + f0 + colo,     dst + 4096 + (p*256 + tid)*8);
    }
  };

  const int NIT = FCk/32;
  stage(0, 0);
  stage(1, 1);
  int cur = 0;
  for (int ks = 0; ks < NIT; ++ks){
    if (ks + 1 < NIT) asm volatile("s_waitcnt vmcnt(4)" ::: "memory");
    else              asm volatile("s_waitcnt vmcnt(0)" ::: "memory");
    __builtin_amdgcn_sched_barrier(0);
    __builtin_amdgcn_s_barrier();
    __builtin_amdgcn_sched_barrier(0);
    const bf16* B0 = smem + cur*8192;
    bf16x8 a[4], b[4];
#pragma unroll
    for (int i = 0; i < 4; ++i){
      a[i] = *(const bf16x8*)&B0[aPos[i]];
      b[i] = *(const bf16x8*)&B0[4096 + bPos[i]];
    }
#pragma unroll
    for (int i = 0; i < 4; ++i)
#pragma unroll
      for (int j = 0; j < 4; ++j)
        acc[i][j] = __builtin_amdgcn_mfma_f32_16x16x32_bf16(a[i], b[j], acc[i][j], 0,0,0);
    asm volatile("s_waitcnt lgkmcnt(0)" ::: "memory");
    __builtin_amdgcn_sched_barrier(0);
    __builtin_amdgcn_s_barrier();
    __builtin_amdgcn_sched_barrier(0);
    if (ks + 2 < NIT) stage(ks + 2, cur);
    cur ^= 1;
  }
  if (Y){
    float* Yb = Y + (size_t)kh*16384*DM;      // per-K-half private buffer
#pragma unroll
    for (int i = 0; i < 4; ++i){
#pragma unroll
      for (int reg = 0; reg < 4; ++reg){
        int m = m0 + wm*64 + i*16 + quad*4 + reg;
        if (m >= cnt) continue;
        float* yr = Yb + (size_t)(rbase + m)*DM + n0;
#pragma unroll
        for (int j = 0; j < 4; ++j)
          yr[wn*64 + j*16 + l15] = acc[i][j][reg];
      }
    }
  } else {
#pragma unroll
    for (int i = 0; i < 4; ++i){
#pragma unroll
      for (int reg = 0; reg < 4; ++reg){
        int m = m0 + wm*64 + i*16 + quad*4 + reg;
        if (m >= cnt) continue;
        int r = le[m];
        int t = r & (TOK-1);
        float g = probs[t*NE + e];
#pragma unroll
        for (int j = 0; j < 4; ++j){
          int n = n0 + wn*64 + j*16 + l15;
          float v = acc[i][j][reg];
          if (addBias) v += b2[e*DM + n] - ce[e*DM + n];
          atomicAdd(&tgt[(size_t)t*DM + n], g*v);
        }
      }
    }
  }
}

// ---------------- launch ----------------
extern "C" void kernel_launch(void* const* d_in, const int* in_sizes, int n_in,
                              void* d_out, int out_size, void* d_ws, size_t ws_size,
                              hipStream_t stream)
{
  (void)in_sizes; (void)n_in; (void)out_size;
  const float* x    = (const float*)d_in[0];
  const float* Wr0  = (const float*)d_in[1];
  const float* W1_0 = (const float*)d_in[2];
  const float* b1_0 = (const float*)d_in[3];
  const float* W2_0 = (const float*)d_in[4];
  const float* b2_0 = (const float*)d_in[5];
  const float* Wr1  = (const float*)d_in[6];
  const float* W1_1 = (const float*)d_in[7];
  const float* b1_1 = (const float*)d_in[8];
  const float* W2_1 = (const float*)d_in[9];
  const float* b2_1 = (const float*)d_in[10];
  float* out = (float*)d_out;

  const size_t MB = (size_t)1 << 20;
  char* base = (char*)d_ws;

  bf16* xhi  = (bf16*)base;                 // 8 MB; phase B: h0b
  bf16* h0b  = (bf16*)base;
  bf16* xlo  = (bf16*)(base + 8*MB);        // 8 MB
  bf16* w10h = (bf16*)(base + 16*MB);       // 16 MB; phase B: w11h
  bf16* w10l = (bf16*)(base + 32*MB);       // 16 MB; phase B: w21h
  bf16* w11h = (bf16*)(base + 16*MB);
  bf16* w21h = (bf16*)(base + 32*MB);
  bf16* w20h = (bf16*)(base + 48*MB);       // 16 MB
  float* h0f = (float*)(base + 64*MB);      // 16 MB (fallback path only)

  char* mp = base + 80*MB;                  // misc ~2.6 MB
  auto take = [&](size_t n) -> char* { char* p = mp; mp += (n + 255) & ~(size_t)255; return p; };
  float* probs0 = (float*)take((size_t)TOK*NE0*4);
  float* probs1 = (float*)take((size_t)TOK*NE1*4);
  int*   idx0   = (int*)  take((size_t)TOK*2*4);
  int*   idx1   = (int*)  take((size_t)TOK*2*4);
  int*   posn0  = (int*)  take((size_t)TOK*2*4);
  int*   posn1  = (int*)  take((size_t)TOK*2*4);
  int*   list0  = (int*)  take((size_t)NE0*TOK*4);
  int*   list1  = (int*)  take((size_t)NE1*TOK*4);
  int*   counts = (int*)  take(256);
  float* c0     = (float*)take((size_t)NE0*DM*4);
  float* c1     = (float*)take((size_t)NE1*DM*4);
  float* Mproj  = (float*)take((size_t)NE0*DFFN*NE1*4);
  double* c0p   = (double*)take(NE0*NE1*8);
  double* b2p   = (double*)take(NE0*NE1*8);
  float* proj   = (float*)take((size_t)2*TOK*NE1*4);

  const size_t fixed = 84*MB;
  int NCH;
  if      (ws_size >= fixed + 128*MB) NCH = 1;
  else if (ws_size >= fixed +  64*MB) NCH = 2;
  else if (ws_size >= fixed +  32*MB) NCH = 4;
  else if (ws_size >= fixed +  16*MB) NCH = 8;
  else return;  // workspace too small: clean validation failure, no fault
  const int FC = DFFN / NCH;
  const size_t chunkB = (size_t)2*TOK*FC*2;       // bytes per bf16 chunk buffer
  bf16* Hb   = (bf16*)(base + fixed);
  bf16* Hlo  = (bf16*)(base + fixed + chunkB);
  // Atomic-free split-K ffn2 (NCH==1 only): Y (2 x 32 MB fp32 halves) reuses the
  // 64 MB Hlo region — level 0: Hlo dead after proj_from_h (stream-ordered before
  // ffn2); level 1: Hlo unused entirely.
  const bool useY = (NCH == 1);
  float* Ybuf = (float*)Hlo;

  hipMemsetAsync(counts, 0, 16*sizeof(int), stream);
  hipMemsetAsync(c0, 0, (size_t)(NE0+NE1)*DM*4, stream);   // c0,c1 contiguous
  if (NCH > 1) hipMemsetAsync(proj, 0, (size_t)2*TOK*NE1*4, stream);

  // prep
  transpose_convert<<<dim3(DFFN/64, DM/64, NE0), 256, 0, stream>>>(W1_0, w10h, w10l, DM, DFFN);
  transpose_convert<<<dim3(DM/64, DFFN/64, NE0), 256, 0, stream>>>(W2_0, w20h, nullptr, DFFN, DM);
  compute_c<<<dim3(NE0*DM/256, 32), 256, 0, stream>>>(W2_0, b1_0, b2_0, c0);
  compute_c<<<dim3(NE1*DM/256, 32), 256, 0, stream>>>(W2_1, b1_1, b2_1, c1);
  compute_M<<<dim3(NE0*DFFN/4), 256, 0, stream>>>(W2_0, Wr1, Mproj, NE0*DFFN);
  compute_cb_proj<<<dim3(8), 256, 0, stream>>>(c0, b2_0, Wr1, c0p, b2p);

  // level 0
  router0_kernel<<<dim3(TOK/4), 256, 0, stream>>>(x, Wr0, probs0, idx0, xhi, xlo);
  build_lists<<<dim3(2*TOK/1024), 1024, 0, stream>>>(idx0, NE0, list0, counts, posn0);
  if (!useY) init_combine<<<dim3(TOK*DM/256), 256, 0, stream>>>(probs0, c0, NE0, h0f);
  for (int c = 0; c < NCH; ++c){
    gemm_ffn1<1><<<dim3(64, FC/128, NE0), 256, 0, stream>>>(
        xhi, xlo, w10h, w10l, b1_0, list0, counts, Hb, Hlo, c*FC, FC);
    proj_from_h<<<dim3(2*TOK/4), 256, 0, stream>>>(Hb, Hlo, FC, c*FC, Mproj,
                                                   list0, counts, proj);
    gemm_ffn2<<<dim3(64, useY ? 8 : 4, NE0), 256, 0, stream>>>(
        Hb, FC, c*FC, w20h, b2_0, c0, probs0, NE0, list0, counts, h0f, (c == 0),
        useY ? Ybuf : nullptr);
  }

  // transition
  transpose_convert<<<dim3(DFFN/64, DM/64, NE1), 256, 0, stream>>>(W1_1, w11h, nullptr, DM, DFFN);
  transpose_convert<<<dim3(DM/64, DFFN/64, NE1), 256, 0, stream>>>(W2_1, w21h, nullptr, DFFN, DM);
  if (useY){
    gather_combine<<<dim3(TOK*DM/4/256), 256, 0, stream>>>(
        Ybuf, posn0, counts, probs0, b2_0, c0, NE0, nullptr, h0b);
  } else {
    f32_to_bf16<<<dim3(TOK*DM/256), 256, 0, stream>>>(h0f, h0b, TOK*DM);
  }
  router1_kernel<<<dim3(TOK/256), 256, 0, stream>>>(proj, probs0, idx0, c0p, b2p,
                                                    probs1, idx1);
  build_lists<<<dim3(2*TOK/1024), 1024, 0, stream>>>(idx1, NE1, list1, counts + NE0, posn1);
  if (!useY) init_combine<<<dim3(TOK*DM/256), 256, 0, stream>>>(probs1, c1, NE1, out);

  // level 1
  for (int c = 0; c < NCH; ++c){
    gemm_ffn1<0><<<dim3(64, FC/128, NE1), 256, 0, stream>>>(
        h0b, nullptr, w11h, nullptr, b1_1, list1, counts + NE0, Hb, nullptr, c*FC, FC);
    gemm_ffn2<<<dim3(64, useY ? 8 : 4, NE1), 256, 0, stream>>>(
        Hb, FC, c*FC, w21h, b2_1, c1, probs1, NE1, list1, counts + NE0, out, (c == 0),
        useY ? Ybuf : nullptr);
  }
  if (useY){
    gather_combine<<<dim3(TOK*DM/4/256), 256, 0, stream>>>(
        Ybuf, posn1, counts + NE0, probs1, b2_1, c1, NE1, out, nullptr);
  }
}